// Round 7
// baseline (3521.484 us; speedup 1.0000x reference)
//
#include <hip/hip_runtime.h>

#define Bc 4
#define Tc 500
#define Uc 100
#define Vc 64
#define G4 2048

typedef __attribute__((ext_vector_type(8))) short short8v;
typedef __attribute__((ext_vector_type(4))) float f32x4;

__device__ __forceinline__ float fsig(float x) {
  return __builtin_amdgcn_rcpf(1.f + __expf(-x));
}
__device__ __forceinline__ float ftanh(float x) {
  float e = __expf(2.f * x);
  return 1.f - 2.f * __builtin_amdgcn_rcpf(e + 1.f);
}
__device__ __forceinline__ short f2bf(float f) {
  unsigned u = __float_as_uint(f);
  unsigned r = (u + 0x7FFFu + ((u >> 16) & 1u)) >> 16;
  return (short)r;
}

__device__ __forceinline__ unsigned ldA(const unsigned* p) {
  return __hip_atomic_load(p, __ATOMIC_RELAXED, __HIP_MEMORY_SCOPE_AGENT);
}
__device__ __forceinline__ void stA(unsigned* p, unsigned v) {
  __hip_atomic_store(p, v, __ATOMIC_RELAXED, __HIP_MEMORY_SCOPE_AGENT);
}

// ---------------- generic GEMM tile (two 256-thread halves per block) -------
template <int ATOMICST>
__device__ __forceinline__ void gemm_tile(
    const float* __restrict__ A, int lda,
    const float* __restrict__ Bw, int ldb,
    const float* __restrict__ bias, const float* __restrict__ bias2,
    float* __restrict__ C, int ldc, int N, int m0, int n0,
    const int* __restrict__ ids, const float* __restrict__ emb,
    int half, int ltid)
{
  __shared__ float As[2][16][65];
  __shared__ float Bs[2][16][65];
  const int tx = ltid & 15, ty = ltid >> 4;
  float acc[4][4] = {};
  for (int k0 = 0; k0 < 512; k0 += 16) {
#pragma unroll
    for (int i = 0; i < 4; ++i) {
      int n = n0 + ty + 16 * i;
      float av = 0.f;
      if (n < N) {
        const float* ar = ids ? (emb + (long)ids[n] * 512) : (A + (long)n * lda);
        av = ar[k0 + tx];
      }
      As[half][tx][ty + 16 * i] = av;
      Bs[half][tx][ty + 16 * i] = Bw[(long)(m0 + ty + 16 * i) * ldb + k0 + tx];
    }
    __syncthreads();
#pragma unroll
    for (int kl = 0; kl < 16; ++kl) {
      float a[4], b[4];
#pragma unroll
      for (int i = 0; i < 4; ++i) a[i] = As[half][kl][ty * 4 + i];
#pragma unroll
      for (int j = 0; j < 4; ++j) b[j] = Bs[half][kl][tx * 4 + j];
#pragma unroll
      for (int i = 0; i < 4; ++i)
#pragma unroll
        for (int j = 0; j < 4; ++j) acc[i][j] += a[i] * b[j];
    }
    __syncthreads();
  }
#pragma unroll
  for (int i = 0; i < 4; ++i) {
    int n = n0 + ty * 4 + i;
    if (n >= N) continue;
#pragma unroll
    for (int j = 0; j < 4; ++j) {
      int m = m0 + tx * 4 + j;
      float v = acc[i][j];
      if (bias)  v += bias[m];
      if (bias2) v += bias2[m];
      if (ATOMICST)
        stA((unsigned*)C + (long)n * ldc + m, __float_as_uint(v));
      else
        C[(long)n * ldc + m] = v;
    }
  }
}

// ---------------- wdc tile: wdc[h][e] = sum_d wd[h][d]*fc_w[d][e] -----------
__device__ void wdc_tile(const float* __restrict__ jw1,
                         const float* __restrict__ fc_w,
                         float* __restrict__ wdc, int n0, int m0,
                         int half, int ltid)
{
  __shared__ float As[2][16][65];
  __shared__ float Bs[2][16][65];
  const int tx = ltid & 15, ty = ltid >> 4;
  float acc[4][4] = {};
  for (int k0 = 0; k0 < 512; k0 += 16) {
#pragma unroll
    for (int i = 0; i < 4; ++i) {
      As[half][tx][ty + 16 * i] = jw1[(long)(n0 + ty + 16 * i) * 1024 + 512 + k0 + tx];
      Bs[half][ty][tx + 16 * i] = fc_w[(long)(k0 + ty) * 512 + m0 + tx + 16 * i];
    }
    __syncthreads();
#pragma unroll
    for (int kl = 0; kl < 16; ++kl) {
      float a[4], b[4];
#pragma unroll
      for (int i = 0; i < 4; ++i) a[i] = As[half][kl][ty * 4 + i];
#pragma unroll
      for (int j = 0; j < 4; ++j) b[j] = Bs[half][kl][tx * 4 + j];
#pragma unroll
      for (int i = 0; i < 4; ++i)
#pragma unroll
        for (int j = 0; j < 4; ++j) acc[i][j] += a[i] * b[j];
    }
    __syncthreads();
  }
#pragma unroll
  for (int i = 0; i < 4; ++i)
#pragma unroll
    for (int j = 0; j < 4; ++j)
      stA((unsigned*)wdc + (long)(n0 + ty * 4 + i) * 512 + m0 + tx * 4 + j,
          __float_as_uint(acc[i][j]));
}

// ---------------- dec tile (advisory flag + per-word NaN backstop) ----------
__device__ void dec_tile(const float* __restrict__ h1s, const float* __restrict__ wdc,
                         const float* __restrict__ jw1, const float* __restrict__ fc_b,
                         const float* __restrict__ jb1, float* __restrict__ decb,
                         const int* __restrict__ f1, int m0, int n0,
                         int half, int ltid)
{
  __shared__ float As[2][16][65];
  __shared__ float Bs[2][16][65];
  __shared__ float biasl[2][64];
  const int tx = ltid & 15, ty = ltid >> 4;
  int u_hi = 0;
  for (int rr = 0; rr < 64; ++rr) {
    int r = n0 + rr;
    if (r < 400) { int u = r % Uc; u_hi = max(u_hi, u + 1); }
  }
  if (ltid < 32)
    while ((int)ldA((const unsigned*)(f1 + ltid * 16)) < u_hi)
      __builtin_amdgcn_s_sleep(8);
  if (ltid < 64) {
    int m = m0 + ltid;
    const float4* wp = (const float4*)(jw1 + (long)m * 1024 + 512);
    const float4* fb = (const float4*)fc_b;
    float bb = jb1[m];
#pragma unroll 8
    for (int d4 = 0; d4 < 128; ++d4) {
      float4 w = wp[d4], f = fb[d4];
      bb += w.x * f.x + w.y * f.y + w.z * f.z + w.w * f.w;
    }
    biasl[half][ltid] = bb;
  }
  __syncthreads();
  const unsigned* h1u = (const unsigned*)h1s;
  const unsigned* wdu = (const unsigned*)wdc;
  float acc[4][4] = {};
  for (int k0 = 0; k0 < 512; k0 += 16) {
    unsigned uA[4], uB[4];
#pragma unroll
    for (int i = 0; i < 4; ++i) {
      int n = n0 + ty + 16 * i;
      uA[i] = (n < 400) ? ldA(h1u + (long)(n % Uc) * G4 + (n / Uc) * 512 + k0 + tx) : 0u;
      uB[i] = ldA(wdu + (long)(m0 + ty + 16 * i) * 512 + k0 + tx);
    }
#pragma unroll
    for (int i = 0; i < 4; ++i) {
      int n = n0 + ty + 16 * i;
      while (uA[i] == 0xFFFFFFFFu)
        uA[i] = ldA(h1u + (long)(n % Uc) * G4 + (n / Uc) * 512 + k0 + tx);
      while (uB[i] == 0xFFFFFFFFu)
        uB[i] = ldA(wdu + (long)(m0 + ty + 16 * i) * 512 + k0 + tx);
      As[half][tx][ty + 16 * i] = __uint_as_float(uA[i]);
      Bs[half][tx][ty + 16 * i] = __uint_as_float(uB[i]);
    }
    __syncthreads();
#pragma unroll
    for (int kl = 0; kl < 16; ++kl) {
      float a[4], b[4];
#pragma unroll
      for (int i = 0; i < 4; ++i) a[i] = As[half][kl][ty * 4 + i];
#pragma unroll
      for (int j = 0; j < 4; ++j) b[j] = Bs[half][kl][tx * 4 + j];
#pragma unroll
      for (int i = 0; i < 4; ++i)
#pragma unroll
        for (int j = 0; j < 4; ++j) acc[i][j] += a[i] * b[j];
    }
    __syncthreads();
  }
#pragma unroll
  for (int i = 0; i < 4; ++i) {
    int n = n0 + ty * 4 + i;
    if (n >= 400) continue;
#pragma unroll
    for (int j = 0; j < 4; ++j)
      decb[(long)n * 512 + m0 + tx * 4 + j] = acc[i][j] + biasl[half][tx * 4 + j];
  }
}

// ---------------- dataflow LSTM recurrence: 48 blocks x 512 threads ----------
// blk 0..15 : layer 0, 32 units each (128 gate rows), whh0 rows in VGPRs.
// blk 16..47: layer 1, 16 units each, wih1(64)+whh1(64) rows in VGPRs.
// Pure NaN dataflow (write-once slots, per-word retry). No end-of-step barrier;
// L1 publishes an ADVISORY flag (dec_tile has full NaN backstop).
__device__ void rec_path(
    const float* __restrict__ ixp0,
    const float* __restrict__ wih1, const float* __restrict__ whh0,
    const float* __restrict__ whh1,
    const float* __restrict__ bih1, const float* __restrict__ bhh1,
    float* __restrict__ h0s, float* __restrict__ h1s,
    float* __restrict__ hO, float* __restrict__ cO, int* __restrict__ flags)
{
  __shared__ float4 hl4[1024];   // [src 2][b 4][quad 128] swizzled
  __shared__ float4 red4[1024];  // [wave 8][rg 32][r 4] -> float4 over b
  const int tid = threadIdx.x;
  const int blk = blockIdx.x;
  const bool isL1 = blk >= 16;
  const int jb = blk - 16;
  const int rg = tid & 31, ks = tid >> 5;
  const int lane = tid & 63, wv = tid >> 6;
  int* f1 = flags + 512;

  // weights: 4 rows x 32 k (8 float4) per thread -> 128 VGPRs; 128 rows/block
  float4 wr4[4][8];
#pragma unroll
  for (int r = 0; r < 4; ++r) {
    int lr = rg * 4 + r;
    const float* wsrc; int grow;
    if (!isL1) { int q = lr >> 5, uu = lr & 31; grow = q * 512 + blk * 32 + uu; wsrc = whh0; }
    else {
      int h2 = lr >> 6, q = (lr >> 4) & 3, uu = lr & 15;
      grow = q * 512 + jb * 16 + uu; wsrc = h2 ? whh1 : wih1;
    }
    const float4* wp = (const float4*)(wsrc + (long)grow * 512 + ks * 32);
#pragma unroll
    for (int jj = 0; jj < 8; ++jj) wr4[r][jj] = wp[jj];
  }

  const int nu = isL1 ? 16 : 32;
  const bool eact = tid < nu * 4;
  const int euu = tid >> 2, eb = tid & 3;
  float creg = 0.f;
  float bgate[4] = {0.f, 0.f, 0.f, 0.f};
  if (isL1 && eact) {
#pragma unroll
    for (int q = 0; q < 4; ++q) {
      int grow = q * 512 + jb * 16 + euu;
      bgate[q] = bih1[grow] + bhh1[grow];
    }
  }

  const unsigned* h0u = (const unsigned*)h0s;
  const unsigned* h1u = (const unsigned*)h1s;
  const unsigned* ixu = (const unsigned*)ixp0;
  const int hsrc = (isL1 && rg >= 16) ? 1 : 0;
  const float* redf = (const float*)red4;

  // stage indices (constant per thread)
  const int sb = tid >> 7, skq = tid & 127;
  const int sc = skq >> 3, so = skq & 7;
  const int sdst = sb * 128 + sc * 8 + ((so + sc) & 7);

  for (int s = 0; s < Uc; ++s) {
    // ---- ixp poll (L0 epilogue threads) ----
    float ixv[4] = {0.f, 0.f, 0.f, 0.f};
    if (!isL1 && eact) {
      const unsigned* ib = ixu + ((long)(eb * Uc + s) * G4 + blk * 32 + euu);
      unsigned g0 = ldA(ib), g1 = ldA(ib + 512), g2 = ldA(ib + 1024), g3 = ldA(ib + 1536);
      while (g0 == 0xFFFFFFFFu) { __builtin_amdgcn_s_sleep(1); g0 = ldA(ib); }
      while (g1 == 0xFFFFFFFFu) { __builtin_amdgcn_s_sleep(1); g1 = ldA(ib + 512); }
      while (g2 == 0xFFFFFFFFu) { __builtin_amdgcn_s_sleep(1); g2 = ldA(ib + 1024); }
      while (g3 == 0xFFFFFFFFu) { __builtin_amdgcn_s_sleep(1); g3 = ldA(ib + 1536); }
      ixv[0] = __uint_as_float(g0); ixv[1] = __uint_as_float(g1);
      ixv[2] = __uint_as_float(g2); ixv[3] = __uint_as_float(g3);
    }

    // ---- gather h (write-once slots, per-word NaN retry) ----
    unsigned ha[4] = {0u, 0u, 0u, 0u}, hb[4] = {0u, 0u, 0u, 0u};
    const unsigned* pa = nullptr; const unsigned* pb = nullptr;
    if (!isL1) { if (s > 0) pa = h0u + (long)(s - 1) * G4 + tid * 4; }
    else {
      pa = h0u + (long)s * G4 + tid * 4;
      if (s > 0) pb = h1u + (long)(s - 1) * G4 + tid * 4;
    }
    if (pa) {
#pragma unroll
      for (int c = 0; c < 4; ++c) ha[c] = ldA(pa + c);
    }
    if (pb) {
#pragma unroll
      for (int c = 0; c < 4; ++c) hb[c] = ldA(pb + c);
    }
    if (pa) {
#pragma unroll
      for (int c = 0; c < 4; ++c)
        while (ha[c] == 0xFFFFFFFFu) { __builtin_amdgcn_s_sleep(1); ha[c] = ldA(pa + c); }
    }
    if (pb) {
#pragma unroll
      for (int c = 0; c < 4; ++c)
        while (hb[c] == 0xFFFFFFFFu) { __builtin_amdgcn_s_sleep(1); hb[c] = ldA(pb + c); }
    }

    // ---- stage into LDS (rotated-quad swizzle) ----
    hl4[sdst] = make_float4(__uint_as_float(ha[0]), __uint_as_float(ha[1]),
                            __uint_as_float(ha[2]), __uint_as_float(ha[3]));
    if (isL1)
      hl4[512 + sdst] = make_float4(__uint_as_float(hb[0]), __uint_as_float(hb[1]),
                                    __uint_as_float(hb[2]), __uint_as_float(hb[3]));
    __syncthreads();

    // ---- dot ----
    float acc[4][4] = {};
#pragma unroll
    for (int j = 0; j < 8; ++j) {
      int pq = hsrc * 512 + ks * 8 + ((j + ks) & 7);
      float4 h0q = hl4[pq];
      float4 h1q = hl4[pq + 128];
      float4 h2q = hl4[pq + 256];
      float4 h3q = hl4[pq + 384];
#pragma unroll
      for (int r = 0; r < 4; ++r) {
        float4 w = wr4[r][j];
        acc[r][0] += w.x * h0q.x + w.y * h0q.y + w.z * h0q.z + w.w * h0q.w;
        acc[r][1] += w.x * h1q.x + w.y * h1q.y + w.z * h1q.z + w.w * h1q.w;
        acc[r][2] += w.x * h2q.x + w.y * h2q.y + w.z * h2q.z + w.w * h2q.w;
        acc[r][3] += w.x * h3q.x + w.y * h3q.y + w.z * h3q.z + w.w * h3q.w;
      }
    }
#pragma unroll
    for (int r = 0; r < 4; ++r)
#pragma unroll
      for (int b = 0; b < 4; ++b)
        acc[r][b] += __shfl_xor(acc[r][b], 32);   // ks-pair reduce
    if (lane < 32) {
#pragma unroll
      for (int r = 0; r < 4; ++r)
        red4[wv * 128 + lane * 4 + r] =
            make_float4(acc[r][0], acc[r][1], acc[r][2], acc[r][3]);
    }
    __syncthreads();

    // ---- epilogue ----
    if (eact) {
      float gv[4];
#pragma unroll
      for (int q = 0; q < 4; ++q) {
        float sv = 0.f;
        int lrA = isL1 ? (q * 16 + euu) : (q * 32 + euu);
#pragma unroll
        for (int w = 0; w < 8; ++w) sv += redf[(w * 128 + lrA) * 4 + eb];
        if (isL1) {
          int lrB = 64 + q * 16 + euu;
#pragma unroll
          for (int w = 0; w < 8; ++w) sv += redf[(w * 128 + lrB) * 4 + eb];
          sv += bgate[q];
        } else {
          sv += ixv[q];
        }
        gv[q] = sv;
      }
      float cn = fsig(gv[1]) * creg + fsig(gv[0]) * ftanh(gv[2]);
      float hn = fsig(gv[3]) * ftanh(cn);
      creg = cn;
      int gu = (isL1 ? jb * 16 : blk * 32) + euu;
      unsigned* dst = (unsigned*)(isL1 ? h1s : h0s) + (long)s * G4 + eb * 512 + gu;
      stA(dst, __float_as_uint(hn));
      if (s == Uc - 1) {
        hO[(isL1 ? G4 : 0) + eb * 512 + gu] = hn;
        cO[(isL1 ? G4 : 0) + eb * 512 + gu] = cn;
      }
      if (isL1 && tid == 0) stA((unsigned*)(f1 + jb * 16), (unsigned)(s + 1));
    }
    // no end-of-step barrier: next-iter hl4/red4 writes are fenced by the
    // two in-loop barriers; h stores propagate autonomously (NaN protocol).
  }
}

// ---------------- fused launch: 348 blocks x 512 threads ----------------
// 0..47 rec | 48..159 ixp (2 tiles/blk) | 160..191 wdc | 192..319 enc | 320..347 dec
__global__ __launch_bounds__(512, 1) void k_fused(
    const int* __restrict__ ids, const float* __restrict__ emb,
    const float* __restrict__ memory,
    const float* __restrict__ w_ih, const float* __restrict__ b_ih,
    const float* __restrict__ b_hh,
    const float* __restrict__ wih1, const float* __restrict__ whh0,
    const float* __restrict__ whh1,
    const float* __restrict__ bih1, const float* __restrict__ bhh1,
    const float* __restrict__ jw1, const float* __restrict__ jb1,
    const float* __restrict__ fc_w, const float* __restrict__ fc_b,
    float* __restrict__ ixp0, float* __restrict__ h0s, float* __restrict__ h1s,
    float* __restrict__ wdc, float* __restrict__ decb, float* __restrict__ encb,
    float* __restrict__ hO, float* __restrict__ cO, int* __restrict__ flags)
{
  const int blk = blockIdx.x;
  const int half = threadIdx.x >> 8;
  const int ltid = threadIdx.x & 255;
  if (blk < 48) {
    rec_path(ixp0, wih1, whh0, whh1, bih1, bhh1, h0s, h1s, hO, cO, flags);
  } else if (blk < 160) {
    static const int nt_ord[7] = {0, 1, 3, 4, 2, 5, 6};
    int t = (blk - 48) * 2 + half;
    gemm_tile<1>(nullptr, 0, w_ih, 512, b_ih, b_hh,
                 ixp0, G4, Bc * Uc, (t % 32) * 64, nt_ord[t / 32] * 64, ids, emb,
                 half, ltid);
  } else if (blk < 192) {
    int t = (blk - 160) * 2 + half;
    wdc_tile(jw1, fc_w, wdc, (t & 7) * 64, (t >> 3) * 64, half, ltid);
  } else if (blk < 320) {
    int t = (blk - 192) * 2 + half;
    gemm_tile<0>(memory, 512, jw1, 1024, nullptr, nullptr,
                 encb, 512, Bc * Tc, (t & 7) * 64, (t >> 3) * 64, nullptr, nullptr,
                 half, ltid);
  } else {
    int t = (blk - 320) * 2 + half;
    dec_tile(h1s, wdc, jw1, fc_b, jb1, decb, flags + 512,
             (t & 7) * 64, (t >> 3) * 64, half, ltid);
  }
}

// ---------------- joint via bf16 MFMA (unchanged from r6) ----------------
__global__ __launch_bounds__(256) void k_jmfma(
    const float* __restrict__ enc, const float* __restrict__ dec,
    const float* __restrict__ jw2, const float* __restrict__ jb2,
    float* __restrict__ out)
{
  __shared__ float el[512];
  __shared__ short th[112][136];
  const int tid = threadIdx.x;
  const int lane = tid & 63, wv = tid >> 6;
  const int bt = blockIdx.x;
  const int b = bt / Tc;
  const int v0 = wv * 16;
  const int vl = lane & 15, kg = lane >> 4;

  short8v breg[16];
#pragma unroll
  for (int ksx = 0; ksx < 16; ++ksx) {
    const float* wp = jw2 + (long)(v0 + vl) * 512 + ksx * 32 + kg * 8;
    float4 x0 = *(const float4*)wp;
    float4 x1 = *(const float4*)(wp + 4);
    short8v t;
    t[0] = f2bf(x0.x); t[1] = f2bf(x0.y); t[2] = f2bf(x0.z); t[3] = f2bf(x0.w);
    t[4] = f2bf(x1.x); t[5] = f2bf(x1.y); t[6] = f2bf(x1.z); t[7] = f2bf(x1.w);
    breg[ksx] = t;
  }
  const float jbv = jb2[v0 + vl];
  for (int i = tid; i < 512; i += 256) el[i] = enc[(long)bt * 512 + i];

  f32x4 acc[7];
#pragma unroll
  for (int ut = 0; ut < 7; ++ut) acc[ut] = (f32x4){0.f, 0.f, 0.f, 0.f};
  __syncthreads();

  const float* dec0 = dec + (long)b * Uc * 512;
  for (int kc = 0; kc < 4; ++kc) {
#pragma unroll 5
    for (int it = 0; it < 50; ++it) {
      int flat = it * 256 + tid;
      int u = flat >> 7, kk = flat & 127;
      float dv = dec0[(long)u * 512 + kc * 128 + kk];
      th[u][kk] = f2bf(ftanh(el[kc * 128 + kk] + dv));
    }
    __syncthreads();
#pragma unroll
    for (int ks4 = 0; ks4 < 4; ++ks4) {
      int ko = ks4 * 32 + kg * 8;
#pragma unroll
      for (int ut = 0; ut < 7; ++ut) {
        short8v a = *(const short8v*)&th[ut * 16 + vl][ko];
        acc[ut] = __builtin_amdgcn_mfma_f32_16x16x32_bf16(a, breg[kc * 4 + ks4],
                                                          acc[ut], 0, 0, 0);
      }
    }
    __syncthreads();
  }
#pragma unroll
  for (int ut = 0; ut < 7; ++ut) {
#pragma unroll
    for (int i = 0; i < 4; ++i) {
      int u = ut * 16 + kg * 4 + i;
      if (u < Uc)
        out[((long)bt * Uc + u) * 64 + v0 + vl] = acc[ut][i] + jbv;
    }
  }
}

extern "C" void kernel_launch(void* const* d_in, const int* in_sizes, int n_in,
                              void* d_out, int out_size, void* d_ws, size_t ws_size,
                              hipStream_t stream)
{
  const int*   ids    = (const int*)d_in[0];
  const float* memory = (const float*)d_in[1];
  const float* emb    = (const float*)d_in[2];
  const float* w_ih   = (const float*)d_in[3];
  const float* w_hh   = (const float*)d_in[4];
  const float* b_ih   = (const float*)d_in[5];
  const float* b_hh   = (const float*)d_in[6];
  const float* fc_w   = (const float*)d_in[7];
  const float* fc_b   = (const float*)d_in[8];
  const float* jw1    = (const float*)d_in[9];
  const float* jb1    = (const float*)d_in[10];
  const float* jw2    = (const float*)d_in[11];
  const float* jb2    = (const float*)d_in[12];
  float* out = (float*)d_out;

  float* wsf = (float*)d_ws;
  int*   flags = (int*)d_ws;                 // 4096 ints (f1 at +512)
  float* ixp0  = wsf + 4096;                 // 819200
  float* h0s   = wsf + 823296;               // 204800
  float* h1s   = wsf + 1028096;              // 204800
  float* wdc   = wsf + 1232896;              // 262144
  float* decb  = wsf + 1495040;              // 204800
  float* encb  = wsf + 1699840;              // 1024000

  float* hO = out + (long)Bc * Tc * Uc * Vc;
  float* cO = hO + 2 * Bc * 512;

  // flags = 0; NaN-init the in-kernel dataflow regions (ixp0,h0s,h1s,wdc)
  hipMemsetAsync(flags, 0, 4096 * 4, stream);
  hipMemsetAsync(ixp0, 0xFF, (size_t)1490944 * 4, stream);

  k_fused<<<348, 512, 0, stream>>>(ids, emb, memory,
                                   w_ih, b_ih, b_hh,
                                   w_ih + (long)G4 * 512,  // wih1
                                   w_hh,                   // whh0
                                   w_hh + (long)G4 * 512,  // whh1
                                   b_ih + G4, b_hh + G4,
                                   jw1, jb1, fc_w, fc_b,
                                   ixp0, h0s, h1s, wdc, decb, encb,
                                   hO, cO, flags);

  k_jmfma<<<2000, 256, 0, stream>>>(encb, decb, jw2, jb2, out);
}

// Round 8
// 991.164 us; speedup vs baseline: 3.5529x; 3.5529x over previous
//
#include <hip/hip_runtime.h>

#define Bc 4
#define Tc 500
#define Uc 100
#define Vc 64
#define G4 2048

typedef __attribute__((ext_vector_type(8))) short short8v;
typedef __attribute__((ext_vector_type(4))) float f32x4;

__device__ __forceinline__ float fsig(float x) {
  return __builtin_amdgcn_rcpf(1.f + __expf(-x));
}
__device__ __forceinline__ float ftanh(float x) {
  float e = __expf(2.f * x);
  return 1.f - 2.f * __builtin_amdgcn_rcpf(e + 1.f);
}
__device__ __forceinline__ short f2bf(float f) {
  unsigned u = __float_as_uint(f);
  unsigned r = (u + 0x7FFFu + ((u >> 16) & 1u)) >> 16;
  return (short)r;
}

__device__ __forceinline__ unsigned ldA(const unsigned* p) {
  return __hip_atomic_load(p, __ATOMIC_RELAXED, __HIP_MEMORY_SCOPE_AGENT);
}
__device__ __forceinline__ void stA(unsigned* p, unsigned v) {
  __hip_atomic_store(p, v, __ATOMIC_RELAXED, __HIP_MEMORY_SCOPE_AGENT);
}
__device__ __forceinline__ void ctrBump(int* c) {
  __hip_atomic_fetch_add(c, 1, __ATOMIC_RELAXED, __HIP_MEMORY_SCOPE_AGENT);
}

// ---------------- generic GEMM tile ----------------
template <int ATOMICST>
__device__ __forceinline__ void gemm_tile(
    const float* __restrict__ A, int lda,
    const float* __restrict__ Bw, int ldb,
    const float* __restrict__ bias, const float* __restrict__ bias2,
    float* __restrict__ C, int ldc, int N, int m0, int n0,
    const int* __restrict__ ids, const float* __restrict__ emb,
    int* __restrict__ ctr)
{
  __shared__ float As[16][65];
  __shared__ float Bs[16][65];
  const int tid = threadIdx.x;
  const int tx = tid & 15, ty = tid >> 4;
  float acc[4][4] = {};
  for (int k0 = 0; k0 < 512; k0 += 16) {
#pragma unroll
    for (int i = 0; i < 4; ++i) {
      int n = n0 + ty + 16 * i;
      float av = 0.f;
      if (n < N) {
        const float* ar = ids ? (emb + (long)ids[n] * 512) : (A + (long)n * lda);
        av = ar[k0 + tx];
      }
      As[tx][ty + 16 * i] = av;
      Bs[tx][ty + 16 * i] = Bw[(long)(m0 + ty + 16 * i) * ldb + k0 + tx];
    }
    __syncthreads();
#pragma unroll
    for (int kl = 0; kl < 16; ++kl) {
      float a[4], b[4];
#pragma unroll
      for (int i = 0; i < 4; ++i) a[i] = As[kl][ty * 4 + i];
#pragma unroll
      for (int j = 0; j < 4; ++j) b[j] = Bs[kl][tx * 4 + j];
#pragma unroll
      for (int i = 0; i < 4; ++i)
#pragma unroll
        for (int j = 0; j < 4; ++j) acc[i][j] += a[i] * b[j];
    }
    __syncthreads();
  }
#pragma unroll
  for (int i = 0; i < 4; ++i) {
    int n = n0 + ty * 4 + i;
    if (n >= N) continue;
#pragma unroll
    for (int j = 0; j < 4; ++j) {
      int m = m0 + tx * 4 + j;
      float v = acc[i][j];
      if (bias)  v += bias[m];
      if (bias2) v += bias2[m];
      if (ATOMICST)
        stA((unsigned*)C + (long)n * ldc + m, __float_as_uint(v));
      else
        C[(long)n * ldc + m] = v;
    }
  }
  if (ctr) {
    __syncthreads();
    if (tid == 0) ctrBump(ctr);
  }
}

// ---------------- wdc tile: wdc[h][e] = sum_d wd[h][d]*fc_w[d][e] ----------------
__device__ void wdc_tile(const float* __restrict__ jw1,
                         const float* __restrict__ fc_w,
                         float* __restrict__ wdc, int n0, int m0)
{
  __shared__ float As[16][65];
  __shared__ float Bs[16][65];
  const int tid = threadIdx.x;
  const int tx = tid & 15, ty = tid >> 4;
  float acc[4][4] = {};
  for (int k0 = 0; k0 < 512; k0 += 16) {
#pragma unroll
    for (int i = 0; i < 4; ++i) {
      As[tx][ty + 16 * i] = jw1[(long)(n0 + ty + 16 * i) * 1024 + 512 + k0 + tx];
      Bs[ty][tx + 16 * i] = fc_w[(long)(k0 + ty) * 512 + m0 + tx + 16 * i];
    }
    __syncthreads();
#pragma unroll
    for (int kl = 0; kl < 16; ++kl) {
      float a[4], b[4];
#pragma unroll
      for (int i = 0; i < 4; ++i) a[i] = As[kl][ty * 4 + i];
#pragma unroll
      for (int j = 0; j < 4; ++j) b[j] = Bs[kl][tx * 4 + j];
#pragma unroll
      for (int i = 0; i < 4; ++i)
#pragma unroll
        for (int j = 0; j < 4; ++j) acc[i][j] += a[i] * b[j];
    }
    __syncthreads();
  }
#pragma unroll
  for (int i = 0; i < 4; ++i)
#pragma unroll
    for (int j = 0; j < 4; ++j)
      stA((unsigned*)wdc + (long)(n0 + ty * 4 + i) * 512 + m0 + tx * 4 + j,
          __float_as_uint(acc[i][j]));
}

// ---------------- dec tile (flag-gated, ldA + NaN backstop) ----------------
__device__ void dec_tile(const float* __restrict__ h1s, const float* __restrict__ wdc,
                         const float* __restrict__ jw1, const float* __restrict__ fc_b,
                         const float* __restrict__ jb1, float* __restrict__ decb,
                         const int* __restrict__ f1, int m0, int n0)
{
  __shared__ float As[16][65];
  __shared__ float Bs[16][65];
  __shared__ float biasl[64];
  const int tid = threadIdx.x;
  const int tx = tid & 15, ty = tid >> 4;
  int u_hi = 0;
  for (int rr = 0; rr < 64; ++rr) {
    int r = n0 + rr;
    if (r < 400) { int u = r % Uc; u_hi = max(u_hi, u + 1); }
  }
  if (tid < 64)
    while ((int)ldA((const unsigned*)(f1 + tid * 16)) < u_hi)
      __builtin_amdgcn_s_sleep(8);
  if (tid < 64) {
    int m = m0 + tid;
    const float4* wp = (const float4*)(jw1 + (long)m * 1024 + 512);
    const float4* fb = (const float4*)fc_b;
    float bb = jb1[m];
#pragma unroll 8
    for (int d4 = 0; d4 < 128; ++d4) {
      float4 w = wp[d4], f = fb[d4];
      bb += w.x * f.x + w.y * f.y + w.z * f.z + w.w * f.w;
    }
    biasl[tid] = bb;
  }
  __syncthreads();
  const unsigned* h1u = (const unsigned*)h1s;
  const unsigned* wdu = (const unsigned*)wdc;
  float acc[4][4] = {};
  for (int k0 = 0; k0 < 512; k0 += 16) {
    unsigned uA[4], uB[4];
#pragma unroll
    for (int i = 0; i < 4; ++i) {
      int n = n0 + ty + 16 * i;
      uA[i] = (n < 400) ? ldA(h1u + (long)(n % Uc) * G4 + (n / Uc) * 512 + k0 + tx) : 0u;
      uB[i] = ldA(wdu + (long)(m0 + ty + 16 * i) * 512 + k0 + tx);
    }
#pragma unroll
    for (int i = 0; i < 4; ++i) {
      int n = n0 + ty + 16 * i;
      while (uA[i] == 0xFFFFFFFFu)
        uA[i] = ldA(h1u + (long)(n % Uc) * G4 + (n / Uc) * 512 + k0 + tx);
      while (uB[i] == 0xFFFFFFFFu)
        uB[i] = ldA(wdu + (long)(m0 + ty + 16 * i) * 512 + k0 + tx);
      As[tx][ty + 16 * i] = __uint_as_float(uA[i]);
      Bs[tx][ty + 16 * i] = __uint_as_float(uB[i]);
    }
    __syncthreads();
#pragma unroll
    for (int kl = 0; kl < 16; ++kl) {
      float a[4], b[4];
#pragma unroll
      for (int i = 0; i < 4; ++i) a[i] = As[kl][ty * 4 + i];
#pragma unroll
      for (int j = 0; j < 4; ++j) b[j] = Bs[kl][tx * 4 + j];
#pragma unroll
      for (int i = 0; i < 4; ++i)
#pragma unroll
        for (int j = 0; j < 4; ++j) acc[i][j] += a[i] * b[j];
    }
    __syncthreads();
  }
#pragma unroll
  for (int i = 0; i < 4; ++i) {
    int n = n0 + ty * 4 + i;
    if (n >= 400) continue;
#pragma unroll
    for (int j = 0; j < 4; ++j)
      stA((unsigned*)decb + (long)n * 512 + m0 + tx * 4 + j,
          __float_as_uint(acc[i][j] + biasl[tx * 4 + j]));
  }
}

// ---------------- heater: pure-VALU load to keep DVFS up during rec window ---
// Polls L1-block-0's step flag (reaches Uc at the final step) once per ~1.5us
// FMA burst; no other memory traffic. Exits promptly; asm sink prevents DCE.
__device__ void heater(const int* f1w)
{
  float a0 = (float)threadIdx.x * 1e-3f + 1.1f;
  float a1 = a0 + 0.17f, a2 = a0 + 0.29f, a3 = a0 + 0.41f;
  float a4 = a0 + 0.53f, a5 = a0 + 0.67f, a6 = a0 + 0.79f, a7 = a0 + 0.91f;
  while ((int)ldA((const unsigned*)f1w) < Uc) {
#pragma unroll 4
    for (int i = 0; i < 256; ++i) {
      a0 = __builtin_fmaf(a0, 1.0000001f, 1.0e-7f);
      a1 = __builtin_fmaf(a1, 1.0000001f, 1.0e-7f);
      a2 = __builtin_fmaf(a2, 1.0000001f, 1.0e-7f);
      a3 = __builtin_fmaf(a3, 1.0000001f, 1.0e-7f);
      a4 = __builtin_fmaf(a4, 1.0000001f, 1.0e-7f);
      a5 = __builtin_fmaf(a5, 1.0000001f, 1.0e-7f);
      a6 = __builtin_fmaf(a6, 1.0000001f, 1.0e-7f);
      a7 = __builtin_fmaf(a7, 1.0000001f, 1.0e-7f);
    }
    asm volatile("" :: "v"(a0), "v"(a1), "v"(a2), "v"(a3),
                       "v"(a4), "v"(a5), "v"(a6), "v"(a7));
  }
}

// ---------------- dataflow LSTM recurrence (r6-proven, unchanged) ----------
__device__ void rec_path(
    const float* __restrict__ ixp0,
    const float* __restrict__ wih1, const float* __restrict__ whh0,
    const float* __restrict__ whh1,
    const float* __restrict__ bih1, const float* __restrict__ bhh1,
    float* __restrict__ h0s, float* __restrict__ h1s,
    float* __restrict__ hO, float* __restrict__ cO, int* __restrict__ flags)
{
  __shared__ float4 hl4[1024];
  __shared__ float4 red4[256];
  const int tid = threadIdx.x;
  const int blk = blockIdx.x;
  const bool isL1 = blk >= 32;
  const int rg = tid & 15, ks = tid >> 4;
  const int lane = tid & 63, wv = tid >> 6;
  const int* f0 = flags;
  const int* f1 = flags + 512;
  unsigned* myflag = (unsigned*)(isL1 ? (f1 + (blk - 32) * 16) : (f0 + blk * 16));

  float4 wr4[4][8];
#pragma unroll
  for (int r = 0; r < 4; ++r) {
    int lr = rg * 4 + r;
    const float* wsrc; int grow;
    if (!isL1) { int q = lr >> 4, uu = lr & 15; grow = q * 512 + blk * 16 + uu; wsrc = whh0; }
    else {
      int jb = blk - 32; int half = lr >> 5, q = (lr >> 3) & 3, uu = lr & 7;
      grow = q * 512 + jb * 8 + uu; wsrc = half ? whh1 : wih1;
    }
    const float4* wp = (const float4*)(wsrc + (long)grow * 512 + ks * 32);
#pragma unroll
    for (int jj = 0; jj < 8; ++jj) wr4[r][jj] = wp[jj];
  }

  const int nu = isL1 ? 8 : 16;
  const bool eact = tid < nu * 4;
  const int euu = tid >> 2, eb = tid & 3;
  float creg = 0.f;
  float bgate[4] = {0.f, 0.f, 0.f, 0.f};
  if (isL1 && eact) {
#pragma unroll
    for (int q = 0; q < 4; ++q) {
      int grow = q * 512 + (blk - 32) * 8 + euu;
      bgate[q] = bih1[grow] + bhh1[grow];
    }
  }

  const unsigned* h0u = (const unsigned*)h0s;
  const unsigned* h1u = (const unsigned*)h1s;
  const unsigned* ixu = (const unsigned*)ixp0;
  const int hsrc = (isL1 && rg >= 8) ? 1 : 0;
  const float* redf = (const float*)red4;

  for (int s = 0; s < Uc; ++s) {
    float ixv[4] = {0.f, 0.f, 0.f, 0.f};
    if (wv == 0) {
      if (!isL1 && eact) {
        const unsigned* ib = ixu + ((long)(eb * Uc + s) * G4 + blk * 16 + euu);
        unsigned g0, g1, g2, g3;
        while (true) {
          g0 = ldA(ib); g1 = ldA(ib + 512); g2 = ldA(ib + 1024); g3 = ldA(ib + 1536);
          if (g0 != 0xFFFFFFFFu && g1 != 0xFFFFFFFFu &&
              g2 != 0xFFFFFFFFu && g3 != 0xFFFFFFFFu) break;
          __builtin_amdgcn_s_sleep(1);
        }
        ixv[0] = __uint_as_float(g0); ixv[1] = __uint_as_float(g1);
        ixv[2] = __uint_as_float(g2); ixv[3] = __uint_as_float(g3);
      }
      if (!isL1) {
        if (s > 0 && lane < 32)
          while ((int)ldA((const unsigned*)(f0 + lane * 16)) < s)
            __builtin_amdgcn_s_sleep(2);
      } else {
        if (lane < 32)
          while ((int)ldA((const unsigned*)(f0 + lane * 16)) < s + 1)
            __builtin_amdgcn_s_sleep(2);
        if (s > 0)
          while ((int)ldA((const unsigned*)(f1 + lane * 16)) < s)
            __builtin_amdgcn_s_sleep(2);
      }
    }
    __syncthreads();

    unsigned ha[8], hb[8];
    {
      const unsigned* pa = nullptr; const unsigned* pb = nullptr;
      if (!isL1) { if (s > 0) pa = h0u + (long)(s - 1) * G4 + tid * 4; }
      else {
        pa = h0u + (long)s * G4 + tid * 4;
        if (s > 0) pb = h1u + (long)(s - 1) * G4 + tid * 4;
      }
      bool done = false;
      while (!done) {
        bool ok = true;
        if (pa) {
#pragma unroll
          for (int it = 0; it < 2; ++it)
#pragma unroll
            for (int c = 0; c < 4; ++c) {
              unsigned u = ldA(pa + it * 1024 + c);
              ha[it * 4 + c] = u; ok &= (u != 0xFFFFFFFFu);
            }
        }
        if (pb) {
#pragma unroll
          for (int it = 0; it < 2; ++it)
#pragma unroll
            for (int c = 0; c < 4; ++c) {
              unsigned u = ldA(pb + it * 1024 + c);
              hb[it * 4 + c] = u; ok &= (u != 0xFFFFFFFFu);
            }
        }
        done = ok;
        if (!done) __builtin_amdgcn_s_sleep(1);
      }
      if (!pa) { for (int i = 0; i < 8; ++i) ha[i] = 0u; }
      if (!pb) { for (int i = 0; i < 8; ++i) hb[i] = 0u; }
    }
#pragma unroll
    for (int it = 0; it < 2; ++it) {
      int qd = tid + it * 256;
      int b = qd >> 7, kq = qd & 127;
      int c = kq >> 3, o = kq & 7;
      int dst = b * 128 + c * 8 + ((o + c) & 7);
      hl4[dst] = make_float4(__uint_as_float(ha[it * 4 + 0]), __uint_as_float(ha[it * 4 + 1]),
                             __uint_as_float(ha[it * 4 + 2]), __uint_as_float(ha[it * 4 + 3]));
      if (isL1)
        hl4[512 + dst] = make_float4(__uint_as_float(hb[it * 4 + 0]), __uint_as_float(hb[it * 4 + 1]),
                                     __uint_as_float(hb[it * 4 + 2]), __uint_as_float(hb[it * 4 + 3]));
    }
    __syncthreads();

    float acc[4][4] = {};
#pragma unroll
    for (int j = 0; j < 8; ++j) {
      int pq = hsrc * 512 + ks * 8 + ((j + ks) & 7);
      float4 h0q = hl4[pq];
      float4 h1q = hl4[pq + 128];
      float4 h2q = hl4[pq + 256];
      float4 h3q = hl4[pq + 384];
#pragma unroll
      for (int r = 0; r < 4; ++r) {
        float4 w = wr4[r][j];
        acc[r][0] += w.x * h0q.x + w.y * h0q.y + w.z * h0q.z + w.w * h0q.w;
        acc[r][1] += w.x * h1q.x + w.y * h1q.y + w.z * h1q.z + w.w * h1q.w;
        acc[r][2] += w.x * h2q.x + w.y * h2q.y + w.z * h2q.z + w.w * h2q.w;
        acc[r][3] += w.x * h3q.x + w.y * h3q.y + w.z * h3q.z + w.w * h3q.w;
      }
    }
#pragma unroll
    for (int r = 0; r < 4; ++r)
#pragma unroll
      for (int b = 0; b < 4; ++b) {
        float v = acc[r][b];
        v += __shfl_xor(v, 16);
        v += __shfl_xor(v, 32);
        acc[r][b] = v;
      }
    if (lane < 16) {
#pragma unroll
      for (int r = 0; r < 4; ++r)
        red4[wv * 64 + lane * 4 + r] =
            make_float4(acc[r][0], acc[r][1], acc[r][2], acc[r][3]);
    }
    __syncthreads();

    if (eact) {
      float gv[4];
#pragma unroll
      for (int q = 0; q < 4; ++q) {
        float sv = 0.f;
        int lrA = isL1 ? (q * 8 + euu) : (q * 16 + euu);
#pragma unroll
        for (int w = 0; w < 4; ++w) sv += redf[(w * 64 + lrA) * 4 + eb];
        if (isL1) {
          int lrB = 32 + q * 8 + euu;
#pragma unroll
          for (int w = 0; w < 4; ++w) sv += redf[(w * 64 + lrB) * 4 + eb];
          sv += bgate[q];
        } else {
          sv += ixv[q];
        }
        gv[q] = sv;
      }
      float cn = fsig(gv[1]) * creg + fsig(gv[0]) * ftanh(gv[2]);
      float hn = fsig(gv[3]) * ftanh(cn);
      creg = cn;
      int gu = (isL1 ? (blk - 32) * 8 : blk * 16) + euu;
      unsigned* dst = (unsigned*)(isL1 ? h1s : h0s) + (long)s * G4 + eb * 512 + gu;
      stA(dst, __float_as_uint(hn));
      if (s == Uc - 1) {
        hO[(isL1 ? G4 : 0) + eb * 512 + gu] = hn;
        cO[(isL1 ? G4 : 0) + eb * 512 + gu] = cn;
      }
    }
    __syncthreads();
    if (tid == 0) stA(myflag, (unsigned)(s + 1));
  }
}

// ---------------- fused launch (r6 structure + heaters) ----------------
// 0..95 rec | 96..319 ixp | 320..383 wdc | 384..639 enc | 640..695 dec | 696.. heater
__global__ __launch_bounds__(256, 1) void k_fused(
    const int* __restrict__ ids, const float* __restrict__ emb,
    const float* __restrict__ memory,
    const float* __restrict__ w_ih, const float* __restrict__ b_ih,
    const float* __restrict__ b_hh,
    const float* __restrict__ wih1, const float* __restrict__ whh0,
    const float* __restrict__ whh1,
    const float* __restrict__ bih1, const float* __restrict__ bhh1,
    const float* __restrict__ jw1, const float* __restrict__ jb1,
    const float* __restrict__ fc_w, const float* __restrict__ fc_b,
    float* __restrict__ ixp0, float* __restrict__ h0s, float* __restrict__ h1s,
    float* __restrict__ wdc, float* __restrict__ decb, float* __restrict__ encb,
    float* __restrict__ hO, float* __restrict__ cO, int* __restrict__ flags)
{
  const int blk = blockIdx.x;
  if (blk < 96) {
    rec_path(ixp0, wih1, whh0, whh1, bih1, bhh1, h0s, h1s, hO, cO, flags);
  } else if (blk < 320) {
    static const int nt_ord[7] = {0, 1, 3, 4, 2, 5, 6};
    int g = blk - 96;
    gemm_tile<1>(nullptr, 0, w_ih, 512, b_ih, b_hh,
                 ixp0, G4, Bc * Uc, (g % 32) * 64, nt_ord[g / 32] * 64, ids, emb,
                 nullptr);
  } else if (blk < 384) {
    int g = blk - 320;
    wdc_tile(jw1, fc_w, wdc, (g & 7) * 64, (g >> 3) * 64);
  } else if (blk < 640) {
    int g = blk - 384;
    gemm_tile<0>(memory, 512, jw1, 1024, nullptr, nullptr,
                 encb, 512, Bc * Tc, (g & 7) * 64, (g >> 3) * 64, nullptr, nullptr,
                 nullptr);
  } else if (blk < 696) {
    int g = blk - 640;
    dec_tile(h1s, wdc, jw1, fc_b, jb1, decb, flags + 512, (g & 7) * 64, (g >> 3) * 64);
  } else {
    heater(flags + 512);   // L1 block 0's step flag; reaches Uc at the end
  }
}

// ---------------- joint via bf16 MFMA (unchanged from r6) ----------------
__global__ __launch_bounds__(256) void k_jmfma(
    const float* __restrict__ enc, const float* __restrict__ dec,
    const float* __restrict__ jw2, const float* __restrict__ jb2,
    float* __restrict__ out)
{
  __shared__ float el[512];
  __shared__ short th[112][136];
  const int tid = threadIdx.x;
  const int lane = tid & 63, wv = tid >> 6;
  const int bt = blockIdx.x;
  const int b = bt / Tc;
  const int v0 = wv * 16;
  const int vl = lane & 15, kg = lane >> 4;

  short8v breg[16];
#pragma unroll
  for (int ksx = 0; ksx < 16; ++ksx) {
    const float* wp = jw2 + (long)(v0 + vl) * 512 + ksx * 32 + kg * 8;
    float4 x0 = *(const float4*)wp;
    float4 x1 = *(const float4*)(wp + 4);
    short8v t;
    t[0] = f2bf(x0.x); t[1] = f2bf(x0.y); t[2] = f2bf(x0.z); t[3] = f2bf(x0.w);
    t[4] = f2bf(x1.x); t[5] = f2bf(x1.y); t[6] = f2bf(x1.z); t[7] = f2bf(x1.w);
    breg[ksx] = t;
  }
  const float jbv = jb2[v0 + vl];
  for (int i = tid; i < 512; i += 256) el[i] = enc[(long)bt * 512 + i];

  f32x4 acc[7];
#pragma unroll
  for (int ut = 0; ut < 7; ++ut) acc[ut] = (f32x4){0.f, 0.f, 0.f, 0.f};
  __syncthreads();

  const float* dec0 = dec + (long)b * Uc * 512;
  for (int kc = 0; kc < 4; ++kc) {
#pragma unroll 5
    for (int it = 0; it < 50; ++it) {
      int flat = it * 256 + tid;
      int u = flat >> 7, kk = flat & 127;
      float dv = dec0[(long)u * 512 + kc * 128 + kk];
      th[u][kk] = f2bf(ftanh(el[kc * 128 + kk] + dv));
    }
    __syncthreads();
#pragma unroll
    for (int ks4 = 0; ks4 < 4; ++ks4) {
      int ko = ks4 * 32 + kg * 8;
#pragma unroll
      for (int ut = 0; ut < 7; ++ut) {
        short8v a = *(const short8v*)&th[ut * 16 + vl][ko];
        acc[ut] = __builtin_amdgcn_mfma_f32_16x16x32_bf16(a, breg[kc * 4 + ks4],
                                                          acc[ut], 0, 0, 0);
      }
    }
    __syncthreads();
  }
#pragma unroll
  for (int ut = 0; ut < 7; ++ut) {
#pragma unroll
    for (int i = 0; i < 4; ++i) {
      int u = ut * 16 + kg * 4 + i;
      if (u < Uc)
        out[((long)bt * Uc + u) * 64 + v0 + vl] = acc[ut][i] + jbv;
    }
  }
}

extern "C" void kernel_launch(void* const* d_in, const int* in_sizes, int n_in,
                              void* d_out, int out_size, void* d_ws, size_t ws_size,
                              hipStream_t stream)
{
  const int*   ids    = (const int*)d_in[0];
  const float* memory = (const float*)d_in[1];
  const float* emb    = (const float*)d_in[2];
  const float* w_ih   = (const float*)d_in[3];
  const float* w_hh   = (const float*)d_in[4];
  const float* b_ih   = (const float*)d_in[5];
  const float* b_hh   = (const float*)d_in[6];
  const float* fc_w   = (const float*)d_in[7];
  const float* fc_b   = (const float*)d_in[8];
  const float* jw1    = (const float*)d_in[9];
  const float* jb1    = (const float*)d_in[10];
  const float* jw2    = (const float*)d_in[11];
  const float* jb2    = (const float*)d_in[12];
  float* out = (float*)d_out;

  float* wsf = (float*)d_ws;
  int*   flags = (int*)d_ws;                 // 4096 ints
  float* ixp0  = wsf + 4096;                 // 819200
  float* h0s   = wsf + 823296;               // 204800
  float* h1s   = wsf + 1028096;              // 204800
  float* wdc   = wsf + 1232896;               // 262144
  float* decb  = wsf + 1495040;              // 204800
  float* encb  = wsf + 1699840;              // 1024000

  float* hO = out + (long)Bc * Tc * Uc * Vc;
  float* cO = hO + 2 * Bc * 512;

  // flags/counters = 0; NaN-init dataflow regions (ixp0,h0s,h1s,wdc,decb,encb)
  hipMemsetAsync(flags, 0, 4096 * 4, stream);
  hipMemsetAsync(ixp0, 0xFF, (size_t)(2723840 - 4096) * 4, stream);

  k_fused<<<1016, 256, 0, stream>>>(ids, emb, memory,
                                    w_ih, b_ih, b_hh,
                                    w_ih + (long)G4 * 512,  // wih1
                                    w_hh,                   // whh0
                                    w_hh + (long)G4 * 512,  // whh1
                                    b_ih + G4, b_hh + G4,
                                    jw1, jb1, fc_w, fc_b,
                                    ixp0, h0s, h1s, wdc, decb, encb,
                                    hO, cO, flags);

  k_jmfma<<<2000, 256, 0, stream>>>(encb, decb, jw2, jb2, out);
}

// Round 9
// 970.373 us; speedup vs baseline: 3.6290x; 1.0214x over previous
//
#include <hip/hip_runtime.h>

#define Bc 4
#define Tc 500
#define Uc 100
#define Vc 64
#define G4 2048

typedef __attribute__((ext_vector_type(8))) short short8v;
typedef __attribute__((ext_vector_type(4))) float f32x4;

__device__ __forceinline__ float fsig(float x) {
  return __builtin_amdgcn_rcpf(1.f + __expf(-x));
}
__device__ __forceinline__ float ftanh(float x) {
  float e = __expf(2.f * x);
  return 1.f - 2.f * __builtin_amdgcn_rcpf(e + 1.f);
}
__device__ __forceinline__ short f2bf(float f) {
  unsigned u = __float_as_uint(f);
  unsigned r = (u + 0x7FFFu + ((u >> 16) & 1u)) >> 16;
  return (short)r;
}

__device__ __forceinline__ unsigned ldA(const unsigned* p) {
  return __hip_atomic_load(p, __ATOMIC_RELAXED, __HIP_MEMORY_SCOPE_AGENT);
}
__device__ __forceinline__ void stA(unsigned* p, unsigned v) {
  __hip_atomic_store(p, v, __ATOMIC_RELAXED, __HIP_MEMORY_SCOPE_AGENT);
}

// ---------------- generic GEMM tile ----------------
template <int ATOMICST>
__device__ __forceinline__ void gemm_tile(
    const float* __restrict__ A, int lda,
    const float* __restrict__ Bw, int ldb,
    const float* __restrict__ bias, const float* __restrict__ bias2,
    float* __restrict__ C, int ldc, int N, int m0, int n0,
    const int* __restrict__ ids, const float* __restrict__ emb)
{
  __shared__ float As[16][65];
  __shared__ float Bs[16][65];
  const int tid = threadIdx.x;
  const int tx = tid & 15, ty = tid >> 4;
  float acc[4][4] = {};
  for (int k0 = 0; k0 < 512; k0 += 16) {
#pragma unroll
    for (int i = 0; i < 4; ++i) {
      int n = n0 + ty + 16 * i;
      float av = 0.f;
      if (n < N) {
        const float* ar = ids ? (emb + (long)ids[n] * 512) : (A + (long)n * lda);
        av = ar[k0 + tx];
      }
      As[tx][ty + 16 * i] = av;
      Bs[tx][ty + 16 * i] = Bw[(long)(m0 + ty + 16 * i) * ldb + k0 + tx];
    }
    __syncthreads();
#pragma unroll
    for (int kl = 0; kl < 16; ++kl) {
      float a[4], b[4];
#pragma unroll
      for (int i = 0; i < 4; ++i) a[i] = As[kl][ty * 4 + i];
#pragma unroll
      for (int j = 0; j < 4; ++j) b[j] = Bs[kl][tx * 4 + j];
#pragma unroll
      for (int i = 0; i < 4; ++i)
#pragma unroll
        for (int j = 0; j < 4; ++j) acc[i][j] += a[i] * b[j];
    }
    __syncthreads();
  }
#pragma unroll
  for (int i = 0; i < 4; ++i) {
    int n = n0 + ty * 4 + i;
    if (n >= N) continue;
#pragma unroll
    for (int j = 0; j < 4; ++j) {
      int m = m0 + tx * 4 + j;
      float v = acc[i][j];
      if (bias)  v += bias[m];
      if (bias2) v += bias2[m];
      if (ATOMICST)
        stA((unsigned*)C + (long)n * ldc + m, __float_as_uint(v));
      else
        C[(long)n * ldc + m] = v;
    }
  }
}

// ---------------- wdc tile: wdc[h][e] = sum_d wd[h][d]*fc_w[d][e] ----------------
__device__ void wdc_tile(const float* __restrict__ jw1,
                         const float* __restrict__ fc_w,
                         float* __restrict__ wdc, int n0, int m0)
{
  __shared__ float As[16][65];
  __shared__ float Bs[16][65];
  const int tid = threadIdx.x;
  const int tx = tid & 15, ty = tid >> 4;
  float acc[4][4] = {};
  for (int k0 = 0; k0 < 512; k0 += 16) {
#pragma unroll
    for (int i = 0; i < 4; ++i) {
      As[tx][ty + 16 * i] = jw1[(long)(n0 + ty + 16 * i) * 1024 + 512 + k0 + tx];
      Bs[ty][tx + 16 * i] = fc_w[(long)(k0 + ty) * 512 + m0 + tx + 16 * i];
    }
    __syncthreads();
#pragma unroll
    for (int kl = 0; kl < 16; ++kl) {
      float a[4], b[4];
#pragma unroll
      for (int i = 0; i < 4; ++i) a[i] = As[kl][ty * 4 + i];
#pragma unroll
      for (int j = 0; j < 4; ++j) b[j] = Bs[kl][tx * 4 + j];
#pragma unroll
      for (int i = 0; i < 4; ++i)
#pragma unroll
        for (int j = 0; j < 4; ++j) acc[i][j] += a[i] * b[j];
    }
    __syncthreads();
  }
#pragma unroll
  for (int i = 0; i < 4; ++i)
#pragma unroll
    for (int j = 0; j < 4; ++j)
      stA((unsigned*)wdc + (long)(n0 + ty * 4 + i) * 512 + m0 + tx * 4 + j,
          __float_as_uint(acc[i][j]));
}

// ---------------- dec tile (advisory flag + per-word NaN backstop) ----------
__device__ void dec_tile(const float* __restrict__ h1s, const float* __restrict__ wdc,
                         const float* __restrict__ jw1, const float* __restrict__ fc_b,
                         const float* __restrict__ jb1, float* __restrict__ decb,
                         const int* __restrict__ f1, int m0, int n0)
{
  __shared__ float As[16][65];
  __shared__ float Bs[16][65];
  __shared__ float biasl[64];
  const int tid = threadIdx.x;
  const int tx = tid & 15, ty = tid >> 4;
  int u_hi = 0;
  for (int rr = 0; rr < 64; ++rr) {
    int r = n0 + rr;
    if (r < 400) { int u = r % Uc; u_hi = max(u_hi, u + 1); }
  }
  if (tid < 32)
    while ((int)ldA((const unsigned*)(f1 + tid * 16)) < u_hi)
      __builtin_amdgcn_s_sleep(8);
  if (tid < 64) {
    int m = m0 + tid;
    const float4* wp = (const float4*)(jw1 + (long)m * 1024 + 512);
    const float4* fb = (const float4*)fc_b;
    float bb = jb1[m];
#pragma unroll 8
    for (int d4 = 0; d4 < 128; ++d4) {
      float4 w = wp[d4], f = fb[d4];
      bb += w.x * f.x + w.y * f.y + w.z * f.z + w.w * f.w;
    }
    biasl[tid] = bb;
  }
  __syncthreads();
  const unsigned* h1u = (const unsigned*)h1s;
  const unsigned* wdu = (const unsigned*)wdc;
  float acc[4][4] = {};
  for (int k0 = 0; k0 < 512; k0 += 16) {
    unsigned uA[4], uB[4];
#pragma unroll
    for (int i = 0; i < 4; ++i) {
      int n = n0 + ty + 16 * i;
      uA[i] = (n < 400) ? ldA(h1u + (long)(n % Uc) * G4 + (n / Uc) * 512 + k0 + tx) : 0u;
      uB[i] = ldA(wdu + (long)(m0 + ty + 16 * i) * 512 + k0 + tx);
    }
#pragma unroll
    for (int i = 0; i < 4; ++i) {
      int n = n0 + ty + 16 * i;
      while (uA[i] == 0xFFFFFFFFu)
        uA[i] = ldA(h1u + (long)(n % Uc) * G4 + (n / Uc) * 512 + k0 + tx);
      while (uB[i] == 0xFFFFFFFFu)
        uB[i] = ldA(wdu + (long)(m0 + ty + 16 * i) * 512 + k0 + tx);
      As[tx][ty + 16 * i] = __uint_as_float(uA[i]);
      Bs[tx][ty + 16 * i] = __uint_as_float(uB[i]);
    }
    __syncthreads();
#pragma unroll
    for (int kl = 0; kl < 16; ++kl) {
      float a[4], b[4];
#pragma unroll
      for (int i = 0; i < 4; ++i) a[i] = As[kl][ty * 4 + i];
#pragma unroll
      for (int j = 0; j < 4; ++j) b[j] = Bs[kl][tx * 4 + j];
#pragma unroll
      for (int i = 0; i < 4; ++i)
#pragma unroll
        for (int j = 0; j < 4; ++j) acc[i][j] += a[i] * b[j];
    }
    __syncthreads();
  }
#pragma unroll
  for (int i = 0; i < 4; ++i) {
    int n = n0 + ty * 4 + i;
    if (n >= 400) continue;
#pragma unroll
    for (int j = 0; j < 4; ++j)
      stA((unsigned*)decb + (long)n * 512 + m0 + tx * 4 + j,
          __float_as_uint(acc[i][j] + biasl[tx * 4 + j]));
  }
}

// ---------------- dataflow LSTM recurrence: pure NaN dataflow, 2 barriers ---
// blk 0..31 : layer 0, 16 units each, whh0 rows (64) in VGPRs.
// blk 32..95: layer 1,  8 units each, wih1(32)+whh1(32) rows in VGPRs.
// No flags, no store-drain: h slots are write-once NaN-initialized; the data
// load itself is the readiness check (per-word retry). L1 publishes an
// ADVISORY step flag for dec_tile (no drain; dec has a full NaN backstop).
__device__ void rec_path(
    const float* __restrict__ ixp0,
    const float* __restrict__ wih1, const float* __restrict__ whh0,
    const float* __restrict__ whh1,
    const float* __restrict__ bih1, const float* __restrict__ bhh1,
    float* __restrict__ h0s, float* __restrict__ h1s,
    float* __restrict__ hO, float* __restrict__ cO, int* __restrict__ flags)
{
  __shared__ float4 hl4[1024];
  __shared__ float4 red4[256];
  const int tid = threadIdx.x;
  const int blk = blockIdx.x;
  const bool isL1 = blk >= 32;
  const int rg = tid & 15, ks = tid >> 4;
  const int lane = tid & 63, wv = tid >> 6;
  int* f1 = flags + 512;

  float4 wr4[4][8];
#pragma unroll
  for (int r = 0; r < 4; ++r) {
    int lr = rg * 4 + r;
    const float* wsrc; int grow;
    if (!isL1) { int q = lr >> 4, uu = lr & 15; grow = q * 512 + blk * 16 + uu; wsrc = whh0; }
    else {
      int jb = blk - 32; int half = lr >> 5, q = (lr >> 3) & 3, uu = lr & 7;
      grow = q * 512 + jb * 8 + uu; wsrc = half ? whh1 : wih1;
    }
    const float4* wp = (const float4*)(wsrc + (long)grow * 512 + ks * 32);
#pragma unroll
    for (int jj = 0; jj < 8; ++jj) wr4[r][jj] = wp[jj];
  }

  const int nu = isL1 ? 8 : 16;
  const bool eact = tid < nu * 4;
  const int euu = tid >> 2, eb = tid & 3;
  float creg = 0.f;
  float bgate[4] = {0.f, 0.f, 0.f, 0.f};
  if (isL1 && eact) {
#pragma unroll
    for (int q = 0; q < 4; ++q) {
      int grow = q * 512 + (blk - 32) * 8 + euu;
      bgate[q] = bih1[grow] + bhh1[grow];
    }
  }

  const unsigned* h0u = (const unsigned*)h0s;
  const unsigned* h1u = (const unsigned*)h1s;
  const unsigned* ixu = (const unsigned*)ixp0;
  const int hsrc = (isL1 && rg >= 8) ? 1 : 0;
  const float* redf = (const float*)red4;

  for (int s = 0; s < Uc; ++s) {
    // ---- gather h: issue loads, then per-word NaN retry ----
    unsigned ha[8], hb[8];
    const unsigned* pa = nullptr; const unsigned* pb = nullptr;
    if (!isL1) { if (s > 0) pa = h0u + (long)(s - 1) * G4 + tid * 4; }
    else {
      pa = h0u + (long)s * G4 + tid * 4;
      if (s > 0) pb = h1u + (long)(s - 1) * G4 + tid * 4;
    }
    if (pa) {
#pragma unroll
      for (int it = 0; it < 2; ++it)
#pragma unroll
        for (int c = 0; c < 4; ++c) ha[it * 4 + c] = ldA(pa + it * 1024 + c);
    } else {
#pragma unroll
      for (int i = 0; i < 8; ++i) ha[i] = 0u;
    }
    if (pb) {
#pragma unroll
      for (int it = 0; it < 2; ++it)
#pragma unroll
        for (int c = 0; c < 4; ++c) hb[it * 4 + c] = ldA(pb + it * 1024 + c);
    } else {
#pragma unroll
      for (int i = 0; i < 8; ++i) hb[i] = 0u;
    }

    // ---- ixp gather for L0 epilogue threads (overlaps with h retries) ----
    float ixv[4] = {0.f, 0.f, 0.f, 0.f};
    if (!isL1 && eact) {
      const unsigned* ib = ixu + ((long)(eb * Uc + s) * G4 + blk * 16 + euu);
      unsigned g0 = ldA(ib), g1 = ldA(ib + 512), g2 = ldA(ib + 1024), g3 = ldA(ib + 1536);
      while (g0 == 0xFFFFFFFFu) { __builtin_amdgcn_s_sleep(1); g0 = ldA(ib); }
      while (g1 == 0xFFFFFFFFu) { __builtin_amdgcn_s_sleep(1); g1 = ldA(ib + 512); }
      while (g2 == 0xFFFFFFFFu) { __builtin_amdgcn_s_sleep(1); g2 = ldA(ib + 1024); }
      while (g3 == 0xFFFFFFFFu) { __builtin_amdgcn_s_sleep(1); g3 = ldA(ib + 1536); }
      ixv[0] = __uint_as_float(g0); ixv[1] = __uint_as_float(g1);
      ixv[2] = __uint_as_float(g2); ixv[3] = __uint_as_float(g3);
    }

    // ---- per-word NaN backstop on h ----
    if (pa) {
#pragma unroll
      for (int i = 0; i < 8; ++i)
        while (ha[i] == 0xFFFFFFFFu) {
          __builtin_amdgcn_s_sleep(1);
          ha[i] = ldA(pa + (i >> 2) * 1024 + (i & 3));
        }
    }
    if (pb) {
#pragma unroll
      for (int i = 0; i < 8; ++i)
        while (hb[i] == 0xFFFFFFFFu) {
          __builtin_amdgcn_s_sleep(1);
          hb[i] = ldA(pb + (i >> 2) * 1024 + (i & 3));
        }
    }

    // ---- stage into LDS (rotated-quad swizzle) ----
#pragma unroll
    for (int it = 0; it < 2; ++it) {
      int qd = tid + it * 256;
      int b = qd >> 7, kq = qd & 127;
      int c = kq >> 3, o = kq & 7;
      int dst = b * 128 + c * 8 + ((o + c) & 7);
      hl4[dst] = make_float4(__uint_as_float(ha[it * 4 + 0]), __uint_as_float(ha[it * 4 + 1]),
                             __uint_as_float(ha[it * 4 + 2]), __uint_as_float(ha[it * 4 + 3]));
      if (isL1)
        hl4[512 + dst] = make_float4(__uint_as_float(hb[it * 4 + 0]), __uint_as_float(hb[it * 4 + 1]),
                                     __uint_as_float(hb[it * 4 + 2]), __uint_as_float(hb[it * 4 + 3]));
    }
    __syncthreads();

    // ---- dot ----
    float acc[4][4] = {};
#pragma unroll
    for (int j = 0; j < 8; ++j) {
      int pq = hsrc * 512 + ks * 8 + ((j + ks) & 7);
      float4 h0q = hl4[pq];
      float4 h1q = hl4[pq + 128];
      float4 h2q = hl4[pq + 256];
      float4 h3q = hl4[pq + 384];
#pragma unroll
      for (int r = 0; r < 4; ++r) {
        float4 w = wr4[r][j];
        acc[r][0] += w.x * h0q.x + w.y * h0q.y + w.z * h0q.z + w.w * h0q.w;
        acc[r][1] += w.x * h1q.x + w.y * h1q.y + w.z * h1q.z + w.w * h1q.w;
        acc[r][2] += w.x * h2q.x + w.y * h2q.y + w.z * h2q.z + w.w * h2q.w;
        acc[r][3] += w.x * h3q.x + w.y * h3q.y + w.z * h3q.z + w.w * h3q.w;
      }
    }
#pragma unroll
    for (int r = 0; r < 4; ++r)
#pragma unroll
      for (int b = 0; b < 4; ++b) {
        float v = acc[r][b];
        v += __shfl_xor(v, 16);
        v += __shfl_xor(v, 32);
        acc[r][b] = v;
      }
    if (lane < 16) {
#pragma unroll
      for (int r = 0; r < 4; ++r)
        red4[wv * 64 + lane * 4 + r] =
            make_float4(acc[r][0], acc[r][1], acc[r][2], acc[r][3]);
    }
    __syncthreads();

    // ---- epilogue: gates -> h,c -> write-once store (no drain, no barrier) --
    if (eact) {
      float gv[4];
#pragma unroll
      for (int q = 0; q < 4; ++q) {
        float sv = 0.f;
        int lrA = isL1 ? (q * 8 + euu) : (q * 16 + euu);
#pragma unroll
        for (int w = 0; w < 4; ++w) sv += redf[(w * 64 + lrA) * 4 + eb];
        if (isL1) {
          int lrB = 32 + q * 8 + euu;
#pragma unroll
          for (int w = 0; w < 4; ++w) sv += redf[(w * 64 + lrB) * 4 + eb];
          sv += bgate[q];
        } else {
          sv += ixv[q];
        }
        gv[q] = sv;
      }
      float cn = fsig(gv[1]) * creg + fsig(gv[0]) * ftanh(gv[2]);
      float hn = fsig(gv[3]) * ftanh(cn);
      creg = cn;
      int gu = (isL1 ? (blk - 32) * 8 : blk * 16) + euu;
      unsigned* dst = (unsigned*)(isL1 ? h1s : h0s) + (long)s * G4 + eb * 512 + gu;
      stA(dst, __float_as_uint(hn));
      if (s == Uc - 1) {
        hO[(isL1 ? G4 : 0) + eb * 512 + gu] = hn;
        cO[(isL1 ? G4 : 0) + eb * 512 + gu] = cn;
      }
      if (isL1 && tid == 0) stA((unsigned*)(f1 + (blk - 32) * 16), (unsigned)(s + 1));
    }
    // no end-of-step barrier: hl4/red4 reuse is protected by the two in-loop
    // barriers; h slots are write-once so readers can never see stale data.
  }
}

// ---------------- fused launch (r6 structure, no heaters) ----------------
// 0..95 rec | 96..319 ixp | 320..383 wdc | 384..639 enc | 640..695 dec
__global__ __launch_bounds__(256, 1) void k_fused(
    const int* __restrict__ ids, const float* __restrict__ emb,
    const float* __restrict__ memory,
    const float* __restrict__ w_ih, const float* __restrict__ b_ih,
    const float* __restrict__ b_hh,
    const float* __restrict__ wih1, const float* __restrict__ whh0,
    const float* __restrict__ whh1,
    const float* __restrict__ bih1, const float* __restrict__ bhh1,
    const float* __restrict__ jw1, const float* __restrict__ jb1,
    const float* __restrict__ fc_w, const float* __restrict__ fc_b,
    float* __restrict__ ixp0, float* __restrict__ h0s, float* __restrict__ h1s,
    float* __restrict__ wdc, float* __restrict__ decb, float* __restrict__ encb,
    float* __restrict__ hO, float* __restrict__ cO, int* __restrict__ flags)
{
  const int blk = blockIdx.x;
  if (blk < 96) {
    rec_path(ixp0, wih1, whh0, whh1, bih1, bhh1, h0s, h1s, hO, cO, flags);
  } else if (blk < 320) {
    static const int nt_ord[7] = {0, 1, 3, 4, 2, 5, 6};
    int g = blk - 96;
    gemm_tile<1>(nullptr, 0, w_ih, 512, b_ih, b_hh,
                 ixp0, G4, Bc * Uc, (g % 32) * 64, nt_ord[g / 32] * 64, ids, emb);
  } else if (blk < 384) {
    int g = blk - 320;
    wdc_tile(jw1, fc_w, wdc, (g & 7) * 64, (g >> 3) * 64);
  } else if (blk < 640) {
    int g = blk - 384;
    gemm_tile<0>(memory, 512, jw1, 1024, nullptr, nullptr,
                 encb, 512, Bc * Tc, (g & 7) * 64, (g >> 3) * 64, nullptr, nullptr);
  } else {
    int g = blk - 640;
    dec_tile(h1s, wdc, jw1, fc_b, jb1, decb, flags + 512, (g & 7) * 64, (g >> 3) * 64);
  }
}

// ---------------- joint via bf16 MFMA (unchanged) ----------------
__global__ __launch_bounds__(256) void k_jmfma(
    const float* __restrict__ enc, const float* __restrict__ dec,
    const float* __restrict__ jw2, const float* __restrict__ jb2,
    float* __restrict__ out)
{
  __shared__ float el[512];
  __shared__ short th[112][136];
  const int tid = threadIdx.x;
  const int lane = tid & 63, wv = tid >> 6;
  const int bt = blockIdx.x;
  const int b = bt / Tc;
  const int v0 = wv * 16;
  const int vl = lane & 15, kg = lane >> 4;

  short8v breg[16];
#pragma unroll
  for (int ksx = 0; ksx < 16; ++ksx) {
    const float* wp = jw2 + (long)(v0 + vl) * 512 + ksx * 32 + kg * 8;
    float4 x0 = *(const float4*)wp;
    float4 x1 = *(const float4*)(wp + 4);
    short8v t;
    t[0] = f2bf(x0.x); t[1] = f2bf(x0.y); t[2] = f2bf(x0.z); t[3] = f2bf(x0.w);
    t[4] = f2bf(x1.x); t[5] = f2bf(x1.y); t[6] = f2bf(x1.z); t[7] = f2bf(x1.w);
    breg[ksx] = t;
  }
  const float jbv = jb2[v0 + vl];
  for (int i = tid; i < 512; i += 256) el[i] = enc[(long)bt * 512 + i];

  f32x4 acc[7];
#pragma unroll
  for (int ut = 0; ut < 7; ++ut) acc[ut] = (f32x4){0.f, 0.f, 0.f, 0.f};
  __syncthreads();

  const float* dec0 = dec + (long)b * Uc * 512;
  for (int kc = 0; kc < 4; ++kc) {
#pragma unroll 5
    for (int it = 0; it < 50; ++it) {
      int flat = it * 256 + tid;
      int u = flat >> 7, kk = flat & 127;
      float dv = dec0[(long)u * 512 + kc * 128 + kk];
      th[u][kk] = f2bf(ftanh(el[kc * 128 + kk] + dv));
    }
    __syncthreads();
#pragma unroll
    for (int ks4 = 0; ks4 < 4; ++ks4) {
      int ko = ks4 * 32 + kg * 8;
#pragma unroll
      for (int ut = 0; ut < 7; ++ut) {
        short8v a = *(const short8v*)&th[ut * 16 + vl][ko];
        acc[ut] = __builtin_amdgcn_mfma_f32_16x16x32_bf16(a, breg[kc * 4 + ks4],
                                                          acc[ut], 0, 0, 0);
      }
    }
    __syncthreads();
  }
#pragma unroll
  for (int ut = 0; ut < 7; ++ut) {
#pragma unroll
    for (int i = 0; i < 4; ++i) {
      int u = ut * 16 + kg * 4 + i;
      if (u < Uc)
        out[((long)bt * Uc + u) * 64 + v0 + vl] = acc[ut][i] + jbv;
    }
  }
}

extern "C" void kernel_launch(void* const* d_in, const int* in_sizes, int n_in,
                              void* d_out, int out_size, void* d_ws, size_t ws_size,
                              hipStream_t stream)
{
  const int*   ids    = (const int*)d_in[0];
  const float* memory = (const float*)d_in[1];
  const float* emb    = (const float*)d_in[2];
  const float* w_ih   = (const float*)d_in[3];
  const float* w_hh   = (const float*)d_in[4];
  const float* b_ih   = (const float*)d_in[5];
  const float* b_hh   = (const float*)d_in[6];
  const float* fc_w   = (const float*)d_in[7];
  const float* fc_b   = (const float*)d_in[8];
  const float* jw1    = (const float*)d_in[9];
  const float* jb1    = (const float*)d_in[10];
  const float* jw2    = (const float*)d_in[11];
  const float* jb2    = (const float*)d_in[12];
  float* out = (float*)d_out;

  float* wsf = (float*)d_ws;
  int*   flags = (int*)d_ws;                 // 4096 ints (f1 at +512)
  float* ixp0  = wsf + 4096;                 // 819200
  float* h0s   = wsf + 823296;               // 204800
  float* h1s   = wsf + 1028096;              // 204800
  float* wdc   = wsf + 1232896;              // 262144
  float* decb  = wsf + 1495040;              // 204800
  float* encb  = wsf + 1699840;              // 1024000

  float* hO = out + (long)Bc * Tc * Uc * Vc;
  float* cO = hO + 2 * Bc * 512;

  // flags = 0; NaN-init dataflow regions (ixp0,h0s,h1s,wdc,decb,encb)
  hipMemsetAsync(flags, 0, 4096 * 4, stream);
  hipMemsetAsync(ixp0, 0xFF, (size_t)(2723840 - 4096) * 4, stream);

  k_fused<<<696, 256, 0, stream>>>(ids, emb, memory,
                                   w_ih, b_ih, b_hh,
                                   w_ih + (long)G4 * 512,  // wih1
                                   w_hh,                   // whh0
                                   w_hh + (long)G4 * 512,  // whh1
                                   b_ih + G4, b_hh + G4,
                                   jw1, jb1, fc_w, fc_b,
                                   ixp0, h0s, h1s, wdc, decb, encb,
                                   hO, cO, flags);

  k_jmfma<<<2000, 256, 0, stream>>>(encb, decb, jw2, jb2, out);
}

// Round 10
// 774.590 us; speedup vs baseline: 4.5463x; 1.2528x over previous
//
#include <hip/hip_runtime.h>

#define Bc 4
#define Tc 500
#define Uc 100
#define Vc 64
#define G4 2048

typedef __attribute__((ext_vector_type(8))) short short8v;
typedef __attribute__((ext_vector_type(4))) float f32x4;
typedef _Float16 h2v __attribute__((ext_vector_type(2)));

__device__ __forceinline__ float fsig(float x) {
  return __builtin_amdgcn_rcpf(1.f + __expf(-x));
}
__device__ __forceinline__ float ftanh(float x) {
  float e = __expf(2.f * x);
  return 1.f - 2.f * __builtin_amdgcn_rcpf(e + 1.f);
}
__device__ __forceinline__ short f2bf(float f) {
  unsigned u = __float_as_uint(f);
  unsigned r = (u + 0x7FFFu + ((u >> 16) & 1u)) >> 16;
  return (short)r;
}

__device__ __forceinline__ unsigned ldA(const unsigned* p) {
  return __hip_atomic_load(p, __ATOMIC_RELAXED, __HIP_MEMORY_SCOPE_AGENT);
}
__device__ __forceinline__ void stA(unsigned* p, unsigned v) {
  __hip_atomic_store(p, v, __ATOMIC_RELAXED, __HIP_MEMORY_SCOPE_AGENT);
}

// ---------------- generic GEMM tile ----------------
template <int ATOMICST>
__device__ __forceinline__ void gemm_tile(
    const float* __restrict__ A, int lda,
    const float* __restrict__ Bw, int ldb,
    const float* __restrict__ bias, const float* __restrict__ bias2,
    float* __restrict__ C, int ldc, int N, int m0, int n0,
    const int* __restrict__ ids, const float* __restrict__ emb)
{
  __shared__ float As[16][65];
  __shared__ float Bs[16][65];
  const int tid = threadIdx.x;
  const int tx = tid & 15, ty = tid >> 4;
  float acc[4][4] = {};
  for (int k0 = 0; k0 < 512; k0 += 16) {
#pragma unroll
    for (int i = 0; i < 4; ++i) {
      int n = n0 + ty + 16 * i;
      float av = 0.f;
      if (n < N) {
        const float* ar = ids ? (emb + (long)ids[n] * 512) : (A + (long)n * lda);
        av = ar[k0 + tx];
      }
      As[tx][ty + 16 * i] = av;
      Bs[tx][ty + 16 * i] = Bw[(long)(m0 + ty + 16 * i) * ldb + k0 + tx];
    }
    __syncthreads();
#pragma unroll
    for (int kl = 0; kl < 16; ++kl) {
      float a[4], b[4];
#pragma unroll
      for (int i = 0; i < 4; ++i) a[i] = As[kl][ty * 4 + i];
#pragma unroll
      for (int j = 0; j < 4; ++j) b[j] = Bs[kl][tx * 4 + j];
#pragma unroll
      for (int i = 0; i < 4; ++i)
#pragma unroll
        for (int j = 0; j < 4; ++j) acc[i][j] += a[i] * b[j];
    }
    __syncthreads();
  }
#pragma unroll
  for (int i = 0; i < 4; ++i) {
    int n = n0 + ty * 4 + i;
    if (n >= N) continue;
#pragma unroll
    for (int j = 0; j < 4; ++j) {
      int m = m0 + tx * 4 + j;
      float v = acc[i][j];
      if (bias)  v += bias[m];
      if (bias2) v += bias2[m];
      if (ATOMICST)
        stA((unsigned*)C + (long)n * ldc + m, __float_as_uint(v));
      else
        C[(long)n * ldc + m] = v;
    }
  }
}

// ---------------- wdc tile: wdc[h][e] = sum_d wd[h][d]*fc_w[d][e] ----------------
__device__ void wdc_tile(const float* __restrict__ jw1,
                         const float* __restrict__ fc_w,
                         float* __restrict__ wdc, int n0, int m0)
{
  __shared__ float As[16][65];
  __shared__ float Bs[16][65];
  const int tid = threadIdx.x;
  const int tx = tid & 15, ty = tid >> 4;
  float acc[4][4] = {};
  for (int k0 = 0; k0 < 512; k0 += 16) {
#pragma unroll
    for (int i = 0; i < 4; ++i) {
      As[tx][ty + 16 * i] = jw1[(long)(n0 + ty + 16 * i) * 1024 + 512 + k0 + tx];
      Bs[ty][tx + 16 * i] = fc_w[(long)(k0 + ty) * 512 + m0 + tx + 16 * i];
    }
    __syncthreads();
#pragma unroll
    for (int kl = 0; kl < 16; ++kl) {
      float a[4], b[4];
#pragma unroll
      for (int i = 0; i < 4; ++i) a[i] = As[kl][ty * 4 + i];
#pragma unroll
      for (int j = 0; j < 4; ++j) b[j] = Bs[kl][tx * 4 + j];
#pragma unroll
      for (int i = 0; i < 4; ++i)
#pragma unroll
        for (int j = 0; j < 4; ++j) acc[i][j] += a[i] * b[j];
    }
    __syncthreads();
  }
#pragma unroll
  for (int i = 0; i < 4; ++i)
#pragma unroll
    for (int j = 0; j < 4; ++j)
      stA((unsigned*)wdc + (long)(n0 + ty * 4 + i) * 512 + m0 + tx * 4 + j,
          __float_as_uint(acc[i][j]));
}

// ---------------- dec tile (advisory flag + per-word NaN backstop) ----------
__device__ void dec_tile(const float* __restrict__ h1s, const float* __restrict__ wdc,
                         const float* __restrict__ jw1, const float* __restrict__ fc_b,
                         const float* __restrict__ jb1, float* __restrict__ decb,
                         const int* __restrict__ f1, int m0, int n0)
{
  __shared__ float As[16][65];
  __shared__ float Bs[16][65];
  __shared__ float biasl[64];
  const int tid = threadIdx.x;
  const int tx = tid & 15, ty = tid >> 4;
  int u_hi = 0;
  for (int rr = 0; rr < 64; ++rr) {
    int r = n0 + rr;
    if (r < 400) { int u = r % Uc; u_hi = max(u_hi, u + 1); }
  }
  if (tid < 32)
    while ((int)ldA((const unsigned*)(f1 + tid * 16)) < u_hi)
      __builtin_amdgcn_s_sleep(8);
  if (tid < 64) {
    int m = m0 + tid;
    const float4* wp = (const float4*)(jw1 + (long)m * 1024 + 512);
    const float4* fb = (const float4*)fc_b;
    float bb = jb1[m];
#pragma unroll 8
    for (int d4 = 0; d4 < 128; ++d4) {
      float4 w = wp[d4], f = fb[d4];
      bb += w.x * f.x + w.y * f.y + w.z * f.z + w.w * f.w;
    }
    biasl[tid] = bb;
  }
  __syncthreads();
  const unsigned* h1u = (const unsigned*)h1s;
  const unsigned* wdu = (const unsigned*)wdc;
  float acc[4][4] = {};
  for (int k0 = 0; k0 < 512; k0 += 16) {
    unsigned uA[4], uB[4];
#pragma unroll
    for (int i = 0; i < 4; ++i) {
      int n = n0 + ty + 16 * i;
      uA[i] = (n < 400) ? ldA(h1u + (long)(n % Uc) * G4 + (n / Uc) * 512 + k0 + tx) : 0u;
      uB[i] = ldA(wdu + (long)(m0 + ty + 16 * i) * 512 + k0 + tx);
    }
#pragma unroll
    for (int i = 0; i < 4; ++i) {
      int n = n0 + ty + 16 * i;
      while (uA[i] == 0xFFFFFFFFu)
        uA[i] = ldA(h1u + (long)(n % Uc) * G4 + (n / Uc) * 512 + k0 + tx);
      while (uB[i] == 0xFFFFFFFFu)
        uB[i] = ldA(wdu + (long)(m0 + ty + 16 * i) * 512 + k0 + tx);
      As[tx][ty + 16 * i] = __uint_as_float(uA[i]);
      Bs[tx][ty + 16 * i] = __uint_as_float(uB[i]);
    }
    __syncthreads();
#pragma unroll
    for (int kl = 0; kl < 16; ++kl) {
      float a[4], b[4];
#pragma unroll
      for (int i = 0; i < 4; ++i) a[i] = As[kl][ty * 4 + i];
#pragma unroll
      for (int j = 0; j < 4; ++j) b[j] = Bs[kl][tx * 4 + j];
#pragma unroll
      for (int i = 0; i < 4; ++i)
#pragma unroll
        for (int j = 0; j < 4; ++j) acc[i][j] += a[i] * b[j];
    }
    __syncthreads();
  }
#pragma unroll
  for (int i = 0; i < 4; ++i) {
    int n = n0 + ty * 4 + i;
    if (n >= 400) continue;
#pragma unroll
    for (int j = 0; j < 4; ++j)
      stA((unsigned*)decb + (long)n * 512 + m0 + tx * 4 + j,
          __float_as_uint(acc[i][j] + biasl[tx * 4 + j]));
  }
}

// ---------------- LSTM recurrence: 48 blocks, fp16 weights + fp16 exchange --
// blk 0..15 : layer 0, 32 units (128 gate rows) each.
// blk 16..47: layer 1, 16 units each (wih1 64 rows + whh1 64 rows).
// Weights fp16 in VGPRs (h2v wr[8][16] = 128 regs); dot via v_dot2_f32_f16.
// h exchanged as packed fp16 pairs in write-once NaN slots (4KB/slot).
// L1 additionally stores fp32 h1 for the dec/fc path.
__device__ void rec_path(
    const float* __restrict__ ixp0,
    const float* __restrict__ wih1, const float* __restrict__ whh0,
    const float* __restrict__ whh1,
    const float* __restrict__ bih1, const float* __restrict__ bhh1,
    unsigned* __restrict__ h0s16, unsigned* __restrict__ h1s16,
    float* __restrict__ h1s32,
    float* __restrict__ hO, float* __restrict__ cO, int* __restrict__ flags)
{
  __shared__ unsigned hl[2048];    // [src 2][b 4][word 256] fp16x2
  __shared__ float4 red4[512];     // [wave 4][rg 16][r 8] -> float4 over b
  const int tid = threadIdx.x;
  const int blk = blockIdx.x;
  const bool isL1 = blk >= 16;
  const int jb = blk - 16;
  const int rg = tid & 15, ks = tid >> 4;
  const int lane = tid & 63, wv = tid >> 6;
  int* f1 = flags + 512;

  // fp16 weight preload: 8 rows x 32 k -> 128 VGPRs
  h2v wr[8][16];
#pragma unroll
  for (int r = 0; r < 8; ++r) {
    int lr = rg * 8 + r;
    const float* wsrc; int grow;
    if (!isL1) { int q = lr >> 5, uu = lr & 31; grow = q * 512 + blk * 32 + uu; wsrc = whh0; }
    else {
      if (lr < 64) { int q = lr >> 4, uu = lr & 15; grow = q * 512 + jb * 16 + uu; wsrc = wih1; }
      else { int l2 = lr - 64; int q = l2 >> 4, uu = l2 & 15; grow = q * 512 + jb * 16 + uu; wsrc = whh1; }
    }
    const float* wp = wsrc + (long)grow * 512 + ks * 32;
#pragma unroll
    for (int jj = 0; jj < 16; ++jj) {
      h2v t; t[0] = (_Float16)wp[2 * jj]; t[1] = (_Float16)wp[2 * jj + 1];
      wr[r][jj] = t;
    }
  }

  const int npair = isL1 ? 8 : 16;
  const bool eact = tid < npair * 4;
  const int ep = tid >> 2, eb = tid & 3;
  float creg[2] = {0.f, 0.f};
  float bgate[2][4];
  if (isL1 && eact) {
#pragma unroll
    for (int o = 0; o < 2; ++o)
#pragma unroll
      for (int q = 0; q < 4; ++q) {
        int grow = q * 512 + jb * 16 + 2 * ep + o;
        bgate[o][q] = bih1[grow] + bhh1[grow];
      }
  }

  const unsigned* ixu = (const unsigned*)ixp0;
  const int hsrc = (isL1 && rg >= 8) ? 1 : 0;
  const float* redf = (const float*)red4;

  for (int s = 0; s < Uc; ++s) {
    // ---- gather packed h (write-once NaN slots, per-word retry) ----
    unsigned ha[4] = {0u, 0u, 0u, 0u}, hb[4] = {0u, 0u, 0u, 0u};
    const unsigned* pa = nullptr; const unsigned* pb = nullptr;
    if (!isL1) { if (s > 0) pa = h0s16 + (long)(s - 1) * 1024 + tid * 4; }
    else {
      pa = h0s16 + (long)s * 1024 + tid * 4;
      if (s > 0) pb = h1s16 + (long)(s - 1) * 1024 + tid * 4;
    }
    if (pa) {
#pragma unroll
      for (int c = 0; c < 4; ++c) ha[c] = ldA(pa + c);
    }
    if (pb) {
#pragma unroll
      for (int c = 0; c < 4; ++c) hb[c] = ldA(pb + c);
    }

    // ---- ixp gather for L0 epilogue threads (overlaps h retries) ----
    float ixv[2][4] = {};
    if (!isL1 && eact) {
      const unsigned* ib = ixu + ((long)(eb * Uc + s) * G4 + blk * 32 + 2 * ep);
#pragma unroll
      for (int o = 0; o < 2; ++o)
#pragma unroll
        for (int q = 0; q < 4; ++q) {
          unsigned g = ldA(ib + o + q * 512);
          while (g == 0xFFFFFFFFu) { __builtin_amdgcn_s_sleep(1); g = ldA(ib + o + q * 512); }
          ixv[o][q] = __uint_as_float(g);
        }
    }

    // ---- per-word NaN backstop ----
    if (pa) {
#pragma unroll
      for (int c = 0; c < 4; ++c)
        while (ha[c] == 0xFFFFFFFFu) { __builtin_amdgcn_s_sleep(1); ha[c] = ldA(pa + c); }
    }
    if (pb) {
#pragma unroll
      for (int c = 0; c < 4; ++c)
        while (hb[c] == 0xFFFFFFFFu) { __builtin_amdgcn_s_sleep(1); hb[c] = ldA(pb + c); }
    }

    // ---- stage to LDS ----
    *(uint4*)&hl[tid * 4] = make_uint4(ha[0], ha[1], ha[2], ha[3]);
    if (isL1)
      *(uint4*)&hl[1024 + tid * 4] = make_uint4(hb[0], hb[1], hb[2], hb[3]);
    __syncthreads();

    // ---- dot via v_dot2_f32_f16 ----
    float acc[8][4] = {};
    const unsigned* hbase = &hl[hsrc * 1024 + ks * 16];
#pragma unroll
    for (int jw = 0; jw < 4; ++jw) {
      unsigned q[4][4];
#pragma unroll
      for (int b = 0; b < 4; ++b) {
        uint4 t = *(const uint4*)&hbase[b * 256 + jw * 4];
        q[b][0] = t.x; q[b][1] = t.y; q[b][2] = t.z; q[b][3] = t.w;
      }
#pragma unroll
      for (int r = 0; r < 8; ++r)
#pragma unroll
        for (int w = 0; w < 4; ++w) {
          h2v wv2 = wr[r][jw * 4 + w];
#pragma unroll
          for (int b = 0; b < 4; ++b)
            acc[r][b] = __builtin_amdgcn_fdot2(
                wv2, __builtin_bit_cast(h2v, q[b][w]), acc[r][b], false);
        }
    }
#pragma unroll
    for (int r = 0; r < 8; ++r)
#pragma unroll
      for (int b = 0; b < 4; ++b) {
        float v = acc[r][b];
        v += __shfl_xor(v, 16);
        v += __shfl_xor(v, 32);
        acc[r][b] = v;
      }
    if (lane < 16) {
#pragma unroll
      for (int r = 0; r < 8; ++r)
        red4[wv * 128 + lane * 8 + r] =
            make_float4(acc[r][0], acc[r][1], acc[r][2], acc[r][3]);
    }
    __syncthreads();

    // ---- epilogue: 2 units per thread, pack fp16 pair, write-once store ----
    if (eact) {
      float hn2[2], cn2[2];
#pragma unroll
      for (int o = 0; o < 2; ++o) {
        int uu = 2 * ep + o;
        float gv[4];
#pragma unroll
        for (int q = 0; q < 4; ++q) {
          int lrA = isL1 ? (q * 16 + uu) : (q * 32 + uu);
          float sv = 0.f;
#pragma unroll
          for (int w = 0; w < 4; ++w)
            sv += redf[(w * 128 + (lrA >> 3) * 8 + (lrA & 7)) * 4 + eb];
          if (isL1) {
            int lrB = 64 + q * 16 + uu;
#pragma unroll
            for (int w = 0; w < 4; ++w)
              sv += redf[(w * 128 + (lrB >> 3) * 8 + (lrB & 7)) * 4 + eb];
            sv += bgate[o][q];
          } else {
            sv += ixv[o][q];
          }
          gv[q] = sv;
        }
        float cn = fsig(gv[1]) * creg[o] + fsig(gv[0]) * ftanh(gv[2]);
        float hn = fsig(gv[3]) * ftanh(cn);
        creg[o] = cn;
        hn2[o] = hn; cn2[o] = cn;
      }
      int gu = (isL1 ? jb * 16 : blk * 32) + 2 * ep;
      h2v hp; hp[0] = (_Float16)hn2[0]; hp[1] = (_Float16)hn2[1];
      unsigned pw = __builtin_bit_cast(unsigned, hp);
      stA((isL1 ? h1s16 : h0s16) + (long)s * 1024 + eb * 256 + (gu >> 1), pw);
      if (isL1) {
        unsigned* d32 = (unsigned*)h1s32 + (long)s * G4 + eb * 512 + gu;
        stA(d32, __float_as_uint(hn2[0]));
        stA(d32 + 1, __float_as_uint(hn2[1]));
      }
      if (s == Uc - 1) {
#pragma unroll
        for (int o = 0; o < 2; ++o) {
          hO[(isL1 ? G4 : 0) + eb * 512 + gu + o] = hn2[o];
          cO[(isL1 ? G4 : 0) + eb * 512 + gu + o] = cn2[o];
        }
      }
      if (isL1 && tid == 0) stA((unsigned*)(f1 + jb * 16), (unsigned)(s + 1));
    }
    // 2 barriers/step; h slots write-once -> no end-of-step barrier needed.
  }
}

// ---------------- fused launch: 648 blocks x 256 threads ----------------
// 0..47 rec | 48..271 ixp | 272..335 wdc | 336..591 enc | 592..647 dec
__global__ __launch_bounds__(256, 1) void k_fused(
    const int* __restrict__ ids, const float* __restrict__ emb,
    const float* __restrict__ memory,
    const float* __restrict__ w_ih, const float* __restrict__ b_ih,
    const float* __restrict__ b_hh,
    const float* __restrict__ wih1, const float* __restrict__ whh0,
    const float* __restrict__ whh1,
    const float* __restrict__ bih1, const float* __restrict__ bhh1,
    const float* __restrict__ jw1, const float* __restrict__ jb1,
    const float* __restrict__ fc_w, const float* __restrict__ fc_b,
    float* __restrict__ ixp0, unsigned* __restrict__ h0s16,
    unsigned* __restrict__ h1s16, float* __restrict__ h1s32,
    float* __restrict__ wdc, float* __restrict__ decb, float* __restrict__ encb,
    float* __restrict__ hO, float* __restrict__ cO, int* __restrict__ flags)
{
  const int blk = blockIdx.x;
  if (blk < 48) {
    rec_path(ixp0, wih1, whh0, whh1, bih1, bhh1, h0s16, h1s16, h1s32,
             hO, cO, flags);
  } else if (blk < 272) {
    static const int nt_ord[7] = {0, 1, 3, 4, 2, 5, 6};
    int g = blk - 48;
    gemm_tile<1>(nullptr, 0, w_ih, 512, b_ih, b_hh,
                 ixp0, G4, Bc * Uc, (g % 32) * 64, nt_ord[g / 32] * 64, ids, emb);
  } else if (blk < 336) {
    int g = blk - 272;
    wdc_tile(jw1, fc_w, wdc, (g & 7) * 64, (g >> 3) * 64);
  } else if (blk < 592) {
    int g = blk - 336;
    gemm_tile<0>(memory, 512, jw1, 1024, nullptr, nullptr,
                 encb, 512, Bc * Tc, (g & 7) * 64, (g >> 3) * 64, nullptr, nullptr);
  } else {
    int g = blk - 592;
    dec_tile(h1s32, wdc, jw1, fc_b, jb1, decb, flags + 512, (g & 7) * 64, (g >> 3) * 64);
  }
}

// ---------------- joint via bf16 MFMA (unchanged) ----------------
__global__ __launch_bounds__(256) void k_jmfma(
    const float* __restrict__ enc, const float* __restrict__ dec,
    const float* __restrict__ jw2, const float* __restrict__ jb2,
    float* __restrict__ out)
{
  __shared__ float el[512];
  __shared__ short th[112][136];
  const int tid = threadIdx.x;
  const int lane = tid & 63, wv = tid >> 6;
  const int bt = blockIdx.x;
  const int b = bt / Tc;
  const int v0 = wv * 16;
  const int vl = lane & 15, kg = lane >> 4;

  short8v breg[16];
#pragma unroll
  for (int ksx = 0; ksx < 16; ++ksx) {
    const float* wp = jw2 + (long)(v0 + vl) * 512 + ksx * 32 + kg * 8;
    float4 x0 = *(const float4*)wp;
    float4 x1 = *(const float4*)(wp + 4);
    short8v t;
    t[0] = f2bf(x0.x); t[1] = f2bf(x0.y); t[2] = f2bf(x0.z); t[3] = f2bf(x0.w);
    t[4] = f2bf(x1.x); t[5] = f2bf(x1.y); t[6] = f2bf(x1.z); t[7] = f2bf(x1.w);
    breg[ksx] = t;
  }
  const float jbv = jb2[v0 + vl];
  for (int i = tid; i < 512; i += 256) el[i] = enc[(long)bt * 512 + i];

  f32x4 acc[7];
#pragma unroll
  for (int ut = 0; ut < 7; ++ut) acc[ut] = (f32x4){0.f, 0.f, 0.f, 0.f};
  __syncthreads();

  const float* dec0 = dec + (long)b * Uc * 512;
  for (int kc = 0; kc < 4; ++kc) {
#pragma unroll 5
    for (int it = 0; it < 50; ++it) {
      int flat = it * 256 + tid;
      int u = flat >> 7, kk = flat & 127;
      float dv = dec0[(long)u * 512 + kc * 128 + kk];
      th[u][kk] = f2bf(ftanh(el[kc * 128 + kk] + dv));
    }
    __syncthreads();
#pragma unroll
    for (int ks4 = 0; ks4 < 4; ++ks4) {
      int ko = ks4 * 32 + kg * 8;
#pragma unroll
      for (int ut = 0; ut < 7; ++ut) {
        short8v a = *(const short8v*)&th[ut * 16 + vl][ko];
        acc[ut] = __builtin_amdgcn_mfma_f32_16x16x32_bf16(a, breg[kc * 4 + ks4],
                                                          acc[ut], 0, 0, 0);
      }
    }
    __syncthreads();
  }
#pragma unroll
  for (int ut = 0; ut < 7; ++ut) {
#pragma unroll
    for (int i = 0; i < 4; ++i) {
      int u = ut * 16 + kg * 4 + i;
      if (u < Uc)
        out[((long)bt * Uc + u) * 64 + v0 + vl] = acc[ut][i] + jbv;
    }
  }
}

extern "C" void kernel_launch(void* const* d_in, const int* in_sizes, int n_in,
                              void* d_out, int out_size, void* d_ws, size_t ws_size,
                              hipStream_t stream)
{
  const int*   ids    = (const int*)d_in[0];
  const float* memory = (const float*)d_in[1];
  const float* emb    = (const float*)d_in[2];
  const float* w_ih   = (const float*)d_in[3];
  const float* w_hh   = (const float*)d_in[4];
  const float* b_ih   = (const float*)d_in[5];
  const float* b_hh   = (const float*)d_in[6];
  const float* fc_w   = (const float*)d_in[7];
  const float* fc_b   = (const float*)d_in[8];
  const float* jw1    = (const float*)d_in[9];
  const float* jb1    = (const float*)d_in[10];
  const float* jw2    = (const float*)d_in[11];
  const float* jb2    = (const float*)d_in[12];
  float* out = (float*)d_out;

  float* wsf = (float*)d_ws;
  int*      flags = (int*)d_ws;                      // 4096 ints (f1 at +512)
  float*    ixp0  = wsf + 4096;                      // 819200
  unsigned* h0s16 = (unsigned*)(wsf + 823296);       // 102400 words
  unsigned* h1s16 = (unsigned*)(wsf + 925696);       // 102400 words
  float*    h1s32 = wsf + 1028096;                   // 204800
  float*    wdc   = wsf + 1232896;                   // 262144
  float*    decb  = wsf + 1495040;                   // 204800
  float*    encb  = wsf + 1699840;                   // 1024000

  float* hO = out + (long)Bc * Tc * Uc * Vc;
  float* cO = hO + 2 * Bc * 512;

  // flags = 0; NaN-init dataflow regions (ixp0,h0s16,h1s16,h1s32,wdc,decb)
  hipMemsetAsync(flags, 0, 4096 * 4, stream);
  hipMemsetAsync(ixp0, 0xFF, (size_t)(1699840 - 4096) * 4, stream);

  k_fused<<<648, 256, 0, stream>>>(ids, emb, memory,
                                   w_ih, b_ih, b_hh,
                                   w_ih + (long)G4 * 512,  // wih1
                                   w_hh,                   // whh0
                                   w_hh + (long)G4 * 512,  // whh1
                                   b_ih + G4, b_hh + G4,
                                   jw1, jb1, fc_w, fc_b,
                                   ixp0, h0s16, h1s16, h1s32, wdc, decb, encb,
                                   hO, cO, flags);

  k_jmfma<<<2000, 256, 0, stream>>>(encb, decb, jw2, jb2, out);
}